// Round 2
// baseline (573.116 us; speedup 1.0000x reference)
//
#include <hip/hip_runtime.h>
#include <hip/hip_bf16.h>

#define NN 8192
#define DD 128
#define DQK 256
#define EE 262144
#define EDGE_DIM 50
#define HID 32
#define SCALE 0.08838834764831845f  // 1/sqrt(128)

using f32x4 = __attribute__((ext_vector_type(4))) float;
using f32x2 = __attribute__((ext_vector_type(2))) float;
using bf16x8 = __attribute__((ext_vector_type(8))) short;  // 8 bf16 = 4 VGPRs
using s16x4 = __attribute__((ext_vector_type(4))) short;

static __device__ __forceinline__ short f2b(float f) {
  __hip_bfloat16 h = __float2bfloat16(f);
  return __builtin_bit_cast(short, h);
}
static __device__ __forceinline__ float b2f(short s) {
  unsigned u = ((unsigned)(unsigned short)s) << 16;
  return __builtin_bit_cast(float, u);
}

// ---------------- K1a: QK[n][0:128]=mag*cos, [128:256]=mag*sin (bf16) --------
__global__ void k1a_qk(const float* __restrict__ mag, const float* __restrict__ phase,
                       short* __restrict__ qkb) {
  int t = blockIdx.x * 256 + threadIdx.x;
  int n = t >> 7, d = t & 127;
  float m = mag[t], p = phase[t];
  float sn, cs;
  __sincosf(p, &sn, &cs);
  qkb[n * DQK + d] = f2b(m * cs);
  qkb[n * DQK + 128 + d] = f2b(m * sn);
}

// ---------------- K1b: VT[f][n] = V[n][f], V=[mag|phase], bf16 ---------------
__global__ void k1b_vt(const float* __restrict__ mag, const float* __restrict__ phase,
                       short* __restrict__ vtb) {
  __shared__ float tile[64][65];
  int bn = blockIdx.x, bd = blockIdx.y, sel = blockIdx.z;
  const float* src = sel ? phase : mag;
  int t = threadIdx.x;
#pragma unroll
  for (int rep = 0; rep < 16; ++rep) {
    int idx = rep * 256 + t;
    int r = idx >> 6, c = idx & 63;
    tile[r][c] = src[(size_t)(bn * 64 + r) * DD + bd * 64 + c];
  }
  __syncthreads();
#pragma unroll
  for (int rep = 0; rep < 16; ++rep) {
    int idx = rep * 256 + t;
    int r = idx >> 6, c = idx & 63;
    vtb[(size_t)(sel * 128 + bd * 64 + r) * NN + bn * 64 + c] = f2b(tile[c][r]);
  }
}

// ---------------- K2: edge MLP bias + row histogram --------------------------
__global__ __launch_bounds__(256) void k2_mlp(
    const float* __restrict__ rbf, const float* __restrict__ W1,
    const float* __restrict__ b1, const float* __restrict__ W2,
    const float* __restrict__ b2, const int* __restrict__ eidx,
    float* __restrict__ bias, int* __restrict__ cnt) {
  __shared__ alignas(16) float w1s[EDGE_DIM * HID];
  __shared__ alignas(16) float b1s[HID];
  __shared__ alignas(16) float w2s[HID];
  __shared__ float b2s;
  int tid = threadIdx.x;
  for (int k = tid; k < EDGE_DIM * HID; k += 256) w1s[k] = W1[k];
  if (tid < HID) { b1s[tid] = b1[tid]; w2s[tid] = W2[tid]; }
  if (tid == 0) b2s = b2[0];
  __syncthreads();
  int e = blockIdx.x * 256 + tid;
  const f32x2* r2 = reinterpret_cast<const f32x2*>(rbf + (size_t)e * EDGE_DIM);
  f32x2 rr[25];
#pragma unroll
  for (int k = 0; k < 25; ++k) rr[k] = r2[k];
  f32x4 h[8];
#pragma unroll
  for (int jj = 0; jj < 8; ++jj) h[jj] = reinterpret_cast<const f32x4*>(b1s)[jj];
#pragma unroll
  for (int k = 0; k < 25; ++k) {
    const f32x4* w0 = reinterpret_cast<const f32x4*>(w1s + (2 * k) * HID);
    const f32x4* w1r = reinterpret_cast<const f32x4*>(w1s + (2 * k + 1) * HID);
#pragma unroll
    for (int jj = 0; jj < 8; ++jj) h[jj] += rr[k].x * w0[jj] + rr[k].y * w1r[jj];
  }
  float outv = b2s;
#pragma unroll
  for (int jj = 0; jj < 8; ++jj) {
    f32x4 x = h[jj];
    f32x4 sl;
#pragma unroll
    for (int q = 0; q < 4; ++q) sl[q] = x[q] / (1.0f + __expf(-x[q]));
    f32x4 pr = sl * reinterpret_cast<const f32x4*>(w2s)[jj];
    outv += pr.x + pr.y + pr.z + pr.w;
  }
  bias[e] = outv;
  atomicAdd(&cnt[eidx[e]], 1);
}

// ---------------- K3: exclusive scan of counts -> rowptr, cursor -------------
__global__ __launch_bounds__(1024) void k3_scan(const int* __restrict__ cnt,
                                                int* __restrict__ rowptr,
                                                int* __restrict__ cursor) {
  __shared__ int sums[1024];
  int t = threadIdx.x;
  int v[8];
  int loc = 0;
#pragma unroll
  for (int k = 0; k < 8; ++k) { v[k] = cnt[t * 8 + k]; loc += v[k]; }
  sums[t] = loc;
  __syncthreads();
  for (int off = 1; off < 1024; off <<= 1) {
    int x = (t >= off) ? sums[t - off] : 0;
    __syncthreads();
    sums[t] += x;
    __syncthreads();
  }
  int excl = sums[t] - loc;
#pragma unroll
  for (int k = 0; k < 8; ++k) {
    rowptr[t * 8 + k] = excl;
    cursor[t * 8 + k] = excl;
    excl += v[k];
  }
  if (t == 1023) rowptr[NN] = excl;
}

// ---------------- K4: scatter edge ids into CSR slots ------------------------
__global__ void k4_scatter(const int* __restrict__ eidx, int* __restrict__ cursor,
                           int* __restrict__ slot) {
  int e = blockIdx.x * 256 + threadIdx.x;
  int i = eidx[e];
  int p = atomicAdd(&cursor[i], 1);
  slot[p] = e;
}

// ---------------- K45: per-edge exp(score) — 8 lanes per edge ----------------
__global__ __launch_bounds__(256) void k45_dot(const int* __restrict__ eidx,
                                               const short* __restrict__ qk,
                                               float* __restrict__ es) {
  int tid = threadIdx.x;
  int e = blockIdx.x * 32 + (tid >> 3);
  int sub = tid & 7;
  int i = eidx[e];
  int j = eidx[EE + e];
  const bf16x8* qa = reinterpret_cast<const bf16x8*>(qk + (size_t)i * DQK + sub * 32);
  const bf16x8* kb = reinterpret_cast<const bf16x8*>(qk + (size_t)j * DQK + sub * 32);
  float sp = 0.f;
#pragma unroll
  for (int t = 0; t < 4; ++t) {
    bf16x8 qa_v = qa[t];
    bf16x8 kb_v = kb[t];
#pragma unroll
    for (int u = 0; u < 8; ++u) sp += b2f(qa_v[u]) * b2f(kb_v[u]);
  }
  sp += __shfl_xor(sp, 1);
  sp += __shfl_xor(sp, 2);
  sp += __shfl_xor(sp, 4);
  if (sub == 0) es[e] = __expf(sp * SCALE);
}

// ---------------- K5: fused dense flash (no max needed) ----------------------
constexpr int BM = 32;
constexpr int BN = 256;
constexpr int PPITCH = 264;  // shorts per LDS P row (+8 pad, keeps 16B align)
constexpr int PBUF = BM * PPITCH;

template <int NSPLIT>
__global__ __launch_bounds__(256, 4) void k5_flash(
    const short* __restrict__ qk,  // [N][256] bf16
    const short* __restrict__ vt,  // [256][N] bf16
    float* __restrict__ nump,      // [NSPLIT][N][256]
    float* __restrict__ denp) {    // [NSPLIT][N]
  constexpr int QCOLS = NN / NSPLIT;
  constexpr int NCHUNK = QCOLS / BN;
  constexpr int GPQ = 8 / NSPLIT;  // blocks per 8-group per col-split
  __shared__ short plds[2 * PBUF];
  __shared__ float dlds[4][BM];
  int b = blockIdx.x;
  // XCD-locality swizzle: dispatch round-robins XCD by blockIdx%8; keep each
  // column split pinned to a fixed XCD subset so its K/V slice stays L2-hot.
  int q = (b & 7) / GPQ;
  int rb = (b >> 3) * GPQ + (b & (GPQ - 1));
  int tid = threadIdx.x;
  int wave = tid >> 6;
  int lane = tid & 63;
  int l15 = lane & 15;
  int quad = lane >> 4;
  int r0 = rb * BM;
  const size_t qrow0 = (size_t)(r0 + l15) * DQK;
  const size_t qrow1 = (size_t)(r0 + 16 + l15) * DQK;
  int cbase = q * QCOLS;

  f32x4 acc[2][4] = {};  // [rowtile][feature-tile]
  float den[2][4] = {};  // [rowtile][reg-row]

#pragma unroll 2
  for (int ch = 0; ch < NCHUNK; ++ch) {
    int c0 = cbase + ch * BN;
    int cw = c0 + wave * 64;  // this wave's 64 S-columns
    // ---- QK^T: S strip 32x64 (Q frags reloaded per ks: L1-hot, saves VGPRs)
    f32x4 s[2][4] = {};
#pragma unroll
    for (int ks = 0; ks < 8; ++ks) {
      int ko = ks * 32 + quad * 8;
      bf16x8 q0 = *reinterpret_cast<const bf16x8*>(qk + qrow0 + ko);
      bf16x8 q1 = *reinterpret_cast<const bf16x8*>(qk + qrow1 + ko);
      bf16x8 kf[4];
#pragma unroll
      for (int ct = 0; ct < 4; ++ct)
        kf[ct] = *reinterpret_cast<const bf16x8*>(
            qk + (size_t)(cw + ct * 16 + l15) * DQK + ko);
#pragma unroll
      for (int ct = 0; ct < 4; ++ct) {
        s[0][ct] = __builtin_amdgcn_mfma_f32_16x16x32_bf16(q0, kf[ct], s[0][ct], 0, 0, 0);
        s[1][ct] = __builtin_amdgcn_mfma_f32_16x16x32_bf16(q1, kf[ct], s[1][ct], 0, 0, 0);
      }
    }
    // ---- exp + den accumulate + P -> LDS buf[ch&1] (C layout) ----
    short* buf = plds + (ch & 1) * PBUF;
#pragma unroll
    for (int rt = 0; rt < 2; ++rt)
#pragma unroll
      for (int ct = 0; ct < 4; ++ct)
#pragma unroll
        for (int r = 0; r < 4; ++r) {
          float p = __expf(s[rt][ct][r] * SCALE);
          den[rt][r] += p;
          buf[(rt * 16 + quad * 4 + r) * PPITCH + wave * 64 + ct * 16 + l15] = f2b(p);
        }
    __syncthreads();  // single barrier/chunk: dbuf covers read-vs-overwrite
    // ---- PV: this wave computes features wave*64..+63, K over 256 cols ------
#pragma unroll
    for (int ks = 0; ks < 8; ++ks) {
      int ko = ks * 32 + quad * 8;
      bf16x8 pa0 = *reinterpret_cast<const bf16x8*>(buf + l15 * PPITCH + ko);
      bf16x8 pa1 = *reinterpret_cast<const bf16x8*>(buf + (16 + l15) * PPITCH + ko);
#pragma unroll
      for (int ft = 0; ft < 4; ++ft) {
        int feat = wave * 64 + ft * 16 + l15;
        bf16x8 vb = *reinterpret_cast<const bf16x8*>(vt + (size_t)feat * NN + c0 + ko);
        acc[0][ft] = __builtin_amdgcn_mfma_f32_16x16x32_bf16(pa0, vb, acc[0][ft], 0, 0, 0);
        acc[1][ft] = __builtin_amdgcn_mfma_f32_16x16x32_bf16(pa1, vb, acc[1][ft], 0, 0, 0);
      }
    }
  }
  // ---- write partial num ----
  float* npB = nump + (size_t)q * NN * DQK;
#pragma unroll
  for (int rt = 0; rt < 2; ++rt)
#pragma unroll
    for (int ft = 0; ft < 4; ++ft) {
      int row = r0 + rt * 16 + quad * 4;
      int feat = wave * 64 + ft * 16 + l15;
#pragma unroll
      for (int r = 0; r < 4; ++r) npB[(size_t)(row + r) * DQK + feat] = acc[rt][ft][r];
    }
  // ---- reduce den across 16 lanes of quad, then across waves ----
#pragma unroll
  for (int rt = 0; rt < 2; ++rt)
#pragma unroll
    for (int r = 0; r < 4; ++r) {
      float d = den[rt][r];
      d += __shfl_xor(d, 1);
      d += __shfl_xor(d, 2);
      d += __shfl_xor(d, 4);
      d += __shfl_xor(d, 8);
      if (l15 == 0) dlds[wave][rt * 16 + quad * 4 + r] = d;
    }
  __syncthreads();
  if (tid < BM) {
    float d = dlds[0][tid] + dlds[1][tid] + dlds[2][tid] + dlds[3][tid];
    denp[q * NN + r0 + tid] = d;
  }
}

// ---------------- K6: per-row sparse correction + combine + normalize --------
__global__ __launch_bounds__(256) void k6_combine(
    const int* __restrict__ eidx, const float* __restrict__ bias,
    const float* __restrict__ es, const int* __restrict__ rowptr,
    const int* __restrict__ slot, const float* __restrict__ mag,
    const float* __restrict__ phase, const float* __restrict__ nump,
    const float* __restrict__ denp, float* __restrict__ out, int nsplit) {
  __shared__ int js[512];
  __shared__ float bs[512];
  __shared__ float ess[512];
  __shared__ int keepf[512];
  __shared__ f32x4 ncl[4][64];
  __shared__ float dcl[4];
  int i = blockIdx.x;
  int tid = threadIdx.x;
  int wave = tid >> 6;
  int lane = tid & 63;
  int start = rowptr[i];
  int cnt = rowptr[i + 1] - start;
  if (cnt > 512) cnt = 512;  // Poisson(32): unreachable in practice
  for (int p = tid; p < cnt; p += 256) {
    int eid = slot[start + p];
    js[p] = eidx[EE + eid];
    bs[p] = bias[eid];
    ess[p] = es[eid];
  }
  __syncthreads();
  // exact duplicate-(i,j) merge: first occurrence keeps summed beta
  {
    int myp[2];
    float mybsum[2];
    int mykeep[2];
    int nmine = 0;
    for (int p = tid; p < cnt; p += 256) {
      int j = js[p];
      float bsum = bs[p];
      int keep = 1;
      for (int qq = 0; qq < cnt; ++qq) {
        if (qq == p || js[qq] != j) continue;
        if (qq < p) { keep = 0; break; }
        bsum += bs[qq];
      }
      myp[nmine] = p; mybsum[nmine] = bsum; mykeep[nmine] = keep; ++nmine;
    }
    __syncthreads();
    for (int k = 0; k < nmine; ++k) { bs[myp[k]] = mybsum[k]; keepf[myp[k]] = mykeep[k]; }
    __syncthreads();
  }
  // edges split across 4 waves; lane f = 4*lane features of [mag|phase]
  const float* vbase = (lane < 32) ? (mag + 4 * lane) : (phase + 4 * lane - 128);
  f32x4 nc = {0.f, 0.f, 0.f, 0.f};
  float denc = 0.f;
  for (int p = wave; p < cnt; p += 4) {
    if (!keepf[p]) continue;
    float delta = ess[p] * expm1f(bs[p]);
    denc += delta;
    f32x4 v = *reinterpret_cast<const f32x4*>(vbase + (size_t)js[p] * DD);
    nc += delta * v;
  }
  ncl[wave][lane] = nc;
  if (lane == 0) dcl[wave] = denc;
  __syncthreads();
  if (wave == 0) {
    f32x4 nd = ncl[0][lane] + ncl[1][lane] + ncl[2][lane] + ncl[3][lane];
    float den = dcl[0] + dcl[1] + dcl[2] + dcl[3];
    for (int qq = 0; qq < nsplit; ++qq) {
      nd += *reinterpret_cast<const f32x4*>(nump + ((size_t)qq * NN + i) * DQK + 4 * lane);
      den += denp[qq * NN + i];
    }
    f32x4 res = nd * (1.0f / den);
    if (lane < 32)
      *reinterpret_cast<f32x4*>(out + (size_t)i * DD + 4 * lane) = res;
    else
      *reinterpret_cast<f32x4*>(out + (size_t)NN * DD + (size_t)i * DD + 4 * lane - 128) = res;
  }
}

// ---------------- workspace layout -------------------------------------------
constexpr size_t OFF_QK = 0;                                  // 4 MiB bf16
constexpr size_t OFF_VT = (size_t)NN * DQK * 2;               // 4 MiB bf16
constexpr size_t OFF_BIAS = OFF_VT + (size_t)DQK * NN * 2;    // 1 MiB f32
constexpr size_t OFF_ES = OFF_BIAS + (size_t)EE * 4;          // 1 MiB f32
constexpr size_t OFF_CNT = OFF_ES + (size_t)EE * 4;
constexpr size_t OFF_ROWPTR = OFF_CNT + (size_t)NN * 4;
constexpr size_t OFF_CURSOR = OFF_ROWPTR + (size_t)(NN + 2) * 4;
constexpr size_t OFF_SLOT = OFF_CURSOR + (size_t)NN * 4;
constexpr size_t OFF_NUMP = (OFF_SLOT + (size_t)EE * 4 + 255) & ~(size_t)255;
constexpr size_t WS_NEED4 = OFF_NUMP + 4ull * NN * DQK * 4 + 4ull * NN * 4;
constexpr size_t WS_NEED2 = OFF_NUMP + 2ull * NN * DQK * 4 + 2ull * NN * 4;

extern "C" void kernel_launch(void* const* d_in, const int* in_sizes, int n_in,
                              void* d_out, int out_size, void* d_ws, size_t ws_size,
                              hipStream_t stream) {
  const float* mag = (const float*)d_in[0];
  const float* phase = (const float*)d_in[1];
  const int* eidx = (const int*)d_in[2];
  const float* rbf = (const float*)d_in[3];
  const float* W1 = (const float*)d_in[4];
  const float* b1 = (const float*)d_in[5];
  const float* W2 = (const float*)d_in[6];
  const float* b2 = (const float*)d_in[7];
  float* out = (float*)d_out;
  char* ws = (char*)d_ws;
  if (ws_size < WS_NEED2) return;
  int nsplit = (ws_size >= WS_NEED4) ? 4 : 2;

  short* qkb = (short*)(ws + OFF_QK);
  short* vtb = (short*)(ws + OFF_VT);
  float* bias = (float*)(ws + OFF_BIAS);
  float* es = (float*)(ws + OFF_ES);
  int* cnt = (int*)(ws + OFF_CNT);
  int* rowptr = (int*)(ws + OFF_ROWPTR);
  int* cursor = (int*)(ws + OFF_CURSOR);
  int* slot = (int*)(ws + OFF_SLOT);
  float* nump = (float*)(ws + OFF_NUMP);
  float* denp = (float*)(ws + OFF_NUMP + (size_t)nsplit * NN * DQK * 4);

  hipMemsetAsync(cnt, 0, (size_t)NN * 4, stream);
  k1a_qk<<<NN * DD / 256, 256, 0, stream>>>(mag, phase, qkb);
  k1b_vt<<<dim3(NN / 64, DD / 64, 2), 256, 0, stream>>>(mag, phase, vtb);
  k2_mlp<<<EE / 256, 256, 0, stream>>>(rbf, W1, b1, W2, b2, eidx, bias, cnt);
  k3_scan<<<1, 1024, 0, stream>>>(cnt, rowptr, cursor);
  k4_scatter<<<EE / 256, 256, 0, stream>>>(eidx, cursor, slot);
  k45_dot<<<EE / 32, 256, 0, stream>>>(eidx, qkb, es);
  if (nsplit == 4)
    k5_flash<4><<<(NN / BM) * 4, 256, 0, stream>>>(qkb, vtb, nump, denp);
  else
    k5_flash<2><<<(NN / BM) * 2, 256, 0, stream>>>(qkb, vtb, nump, denp);
  k6_combine<<<NN, 256, 0, stream>>>(eidx, bias, es, rowptr, slot, mag, phase, nump,
                                     denp, out, nsplit);
}

// Round 3
// 485.361 us; speedup vs baseline: 1.1808x; 1.1808x over previous
//
#include <hip/hip_runtime.h>
#include <hip/hip_bf16.h>

#define NN 8192
#define DD 128
#define DQK 256
#define EE 262144
#define EDGE_DIM 50
#define HID 32
#define SCALE 0.08838834764831845f          // 1/sqrt(128)
#define SCALE_LOG2E 0.12752455522410585f    // SCALE * log2(e)

using f32x4 = __attribute__((ext_vector_type(4))) float;
using f32x2 = __attribute__((ext_vector_type(2))) float;
using bf16x8 = __attribute__((ext_vector_type(8))) short;  // 8 bf16 = 4 VGPRs
using s16x4 = __attribute__((ext_vector_type(4))) short;

static __device__ __forceinline__ short f2b(float f) {
  __hip_bfloat16 h = __float2bfloat16(f);
  return __builtin_bit_cast(short, h);
}
static __device__ __forceinline__ float b2f(short s) {
  unsigned u = ((unsigned)(unsigned short)s) << 16;
  return __builtin_bit_cast(float, u);
}

// ---------------- K1a: QK[n][0:128]=mag*cos, [128:256]=mag*sin (bf16) --------
__global__ void k1a_qk(const float* __restrict__ mag, const float* __restrict__ phase,
                       short* __restrict__ qkb) {
  int t = blockIdx.x * 256 + threadIdx.x;
  int n = t >> 7, d = t & 127;
  float m = mag[t], p = phase[t];
  float sn, cs;
  __sincosf(p, &sn, &cs);
  qkb[n * DQK + d] = f2b(m * cs);
  qkb[n * DQK + 128 + d] = f2b(m * sn);
}

// ---------------- K1b: VT[f][n] = V[n][f], V=[mag|phase], bf16 ---------------
__global__ void k1b_vt(const float* __restrict__ mag, const float* __restrict__ phase,
                       short* __restrict__ vtb) {
  __shared__ float tile[64][65];
  int bn = blockIdx.x, bd = blockIdx.y, sel = blockIdx.z;
  const float* src = sel ? phase : mag;
  int t = threadIdx.x;
#pragma unroll
  for (int rep = 0; rep < 16; ++rep) {
    int idx = rep * 256 + t;
    int r = idx >> 6, c = idx & 63;
    tile[r][c] = src[(size_t)(bn * 64 + r) * DD + bd * 64 + c];
  }
  __syncthreads();
#pragma unroll
  for (int rep = 0; rep < 16; ++rep) {
    int idx = rep * 256 + t;
    int r = idx >> 6, c = idx & 63;
    vtb[(size_t)(sel * 128 + bd * 64 + r) * NN + bn * 64 + c] = f2b(tile[c][r]);
  }
}

// ---------------- K2: edge MLP bias + row histogram --------------------------
__global__ __launch_bounds__(256) void k2_mlp(
    const float* __restrict__ rbf, const float* __restrict__ W1,
    const float* __restrict__ b1, const float* __restrict__ W2,
    const float* __restrict__ b2, const int* __restrict__ eidx,
    float* __restrict__ bias, int* __restrict__ cnt) {
  __shared__ alignas(16) float w1s[EDGE_DIM * HID];
  __shared__ alignas(16) float b1s[HID];
  __shared__ alignas(16) float w2s[HID];
  __shared__ float b2s;
  int tid = threadIdx.x;
  for (int k = tid; k < EDGE_DIM * HID; k += 256) w1s[k] = W1[k];
  if (tid < HID) { b1s[tid] = b1[tid]; w2s[tid] = W2[tid]; }
  if (tid == 0) b2s = b2[0];
  __syncthreads();
  int e = blockIdx.x * 256 + tid;
  const f32x2* r2 = reinterpret_cast<const f32x2*>(rbf + (size_t)e * EDGE_DIM);
  f32x2 rr[25];
#pragma unroll
  for (int k = 0; k < 25; ++k) rr[k] = r2[k];
  f32x4 h[8];
#pragma unroll
  for (int jj = 0; jj < 8; ++jj) h[jj] = reinterpret_cast<const f32x4*>(b1s)[jj];
#pragma unroll
  for (int k = 0; k < 25; ++k) {
    const f32x4* w0 = reinterpret_cast<const f32x4*>(w1s + (2 * k) * HID);
    const f32x4* w1r = reinterpret_cast<const f32x4*>(w1s + (2 * k + 1) * HID);
#pragma unroll
    for (int jj = 0; jj < 8; ++jj) h[jj] += rr[k].x * w0[jj] + rr[k].y * w1r[jj];
  }
  float outv = b2s;
#pragma unroll
  for (int jj = 0; jj < 8; ++jj) {
    f32x4 x = h[jj];
    f32x4 sl;
#pragma unroll
    for (int q = 0; q < 4; ++q) sl[q] = x[q] / (1.0f + __expf(-x[q]));
    f32x4 pr = sl * reinterpret_cast<const f32x4*>(w2s)[jj];
    outv += pr.x + pr.y + pr.z + pr.w;
  }
  bias[e] = outv;
  atomicAdd(&cnt[eidx[e]], 1);
}

// ---------------- K3: exclusive scan of counts -> rowptr, cursor -------------
__global__ __launch_bounds__(1024) void k3_scan(const int* __restrict__ cnt,
                                                int* __restrict__ rowptr,
                                                int* __restrict__ cursor) {
  __shared__ int sums[1024];
  int t = threadIdx.x;
  int v[8];
  int loc = 0;
#pragma unroll
  for (int k = 0; k < 8; ++k) { v[k] = cnt[t * 8 + k]; loc += v[k]; }
  sums[t] = loc;
  __syncthreads();
  for (int off = 1; off < 1024; off <<= 1) {
    int x = (t >= off) ? sums[t - off] : 0;
    __syncthreads();
    sums[t] += x;
    __syncthreads();
  }
  int excl = sums[t] - loc;
#pragma unroll
  for (int k = 0; k < 8; ++k) {
    rowptr[t * 8 + k] = excl;
    cursor[t * 8 + k] = excl;
    excl += v[k];
  }
  if (t == 1023) rowptr[NN] = excl;
}

// ---------------- K4: scatter edge ids into CSR slots ------------------------
__global__ void k4_scatter(const int* __restrict__ eidx, int* __restrict__ cursor,
                           int* __restrict__ slot) {
  int e = blockIdx.x * 256 + threadIdx.x;
  int i = eidx[e];
  int p = atomicAdd(&cursor[i], 1);
  slot[p] = e;
}

// ---------------- K45: per-edge exp(score) — 8 lanes per edge ----------------
__global__ __launch_bounds__(256) void k45_dot(const int* __restrict__ eidx,
                                               const short* __restrict__ qk,
                                               float* __restrict__ es) {
  int tid = threadIdx.x;
  int e = blockIdx.x * 32 + (tid >> 3);
  int sub = tid & 7;
  int i = eidx[e];
  int j = eidx[EE + e];
  const bf16x8* qa = reinterpret_cast<const bf16x8*>(qk + (size_t)i * DQK + sub * 32);
  const bf16x8* kb = reinterpret_cast<const bf16x8*>(qk + (size_t)j * DQK + sub * 32);
  float sp = 0.f;
#pragma unroll
  for (int t = 0; t < 4; ++t) {
    bf16x8 qa_v = qa[t];
    bf16x8 kb_v = kb[t];
#pragma unroll
    for (int u = 0; u < 8; ++u) sp += b2f(qa_v[u]) * b2f(kb_v[u]);
  }
  sp += __shfl_xor(sp, 1);
  sp += __shfl_xor(sp, 2);
  sp += __shfl_xor(sp, 4);
  if (sub == 0) es[e] = __expf(sp * SCALE);
}

// ---------------- K5: fused dense flash (no max needed) ----------------------
// Q-fragments register-resident (no spill: launch_bounds(.,2) keeps budget 256).
// Occupancy comes from grid: NSPLIT=4 -> 1024 blocks -> 4 blocks/CU available.
constexpr int BM = 32;
constexpr int BN = 256;
constexpr int PPITCH = 264;  // shorts per LDS P row (+8 pad, keeps 16B align)
constexpr int PBUF = BM * PPITCH;

template <int NSPLIT>
__global__ __launch_bounds__(256, 2) void k5_flash(
    const short* __restrict__ qk,  // [N][256] bf16
    const short* __restrict__ vt,  // [256][N] bf16
    float* __restrict__ nump,      // [NSPLIT][N][256]
    float* __restrict__ denp) {    // [NSPLIT][N]
  constexpr int QCOLS = NN / NSPLIT;
  constexpr int NCHUNK = QCOLS / BN;
  constexpr int GPQ = 8 / NSPLIT;  // blocks per 8-group per col-split
  __shared__ short plds[2 * PBUF];
  __shared__ float dlds[4][BM];
  int b = blockIdx.x;
  // XCD-locality swizzle: dispatch round-robins XCD by blockIdx%8; keep each
  // column split pinned to a fixed XCD subset so its K/V slice stays L2-hot.
  int q = (b & 7) / GPQ;
  int rb = (b >> 3) * GPQ + (b & (GPQ - 1));
  int tid = threadIdx.x;
  int wave = tid >> 6;
  int lane = tid & 63;
  int l15 = lane & 15;
  int quad = lane >> 4;
  int r0 = rb * BM;
  int cbase = q * QCOLS;

  // Q fragments resident: A[m=l15][k=quad*8+j], per rowtile/kstep
  bf16x8 qf[2][8];
#pragma unroll
  for (int rt = 0; rt < 2; ++rt) {
    const bf16x8* qrow =
        reinterpret_cast<const bf16x8*>(qk + (size_t)(r0 + rt * 16 + l15) * DQK);
#pragma unroll
    for (int ks = 0; ks < 8; ++ks) qf[rt][ks] = qrow[ks * 4 + quad];
  }
  f32x4 acc[2][4] = {};  // [rowtile][feature-tile]
  float den[2][4] = {};  // [rowtile][reg-row]

  for (int ch = 0; ch < NCHUNK; ++ch) {
    int c0 = cbase + ch * BN;
    int cw = c0 + wave * 64;  // this wave's 64 S-columns
    // ---- QK^T: S strip 32x64 ----
    f32x4 s[2][4] = {};
#pragma unroll
    for (int ks = 0; ks < 8; ++ks) {
      int ko = ks * 32 + quad * 8;
      bf16x8 kf[4];
#pragma unroll
      for (int ct = 0; ct < 4; ++ct)
        kf[ct] = *reinterpret_cast<const bf16x8*>(
            qk + (size_t)(cw + ct * 16 + l15) * DQK + ko);
#pragma unroll
      for (int ct = 0; ct < 4; ++ct) {
        s[0][ct] = __builtin_amdgcn_mfma_f32_16x16x32_bf16(qf[0][ks], kf[ct], s[0][ct], 0, 0, 0);
        s[1][ct] = __builtin_amdgcn_mfma_f32_16x16x32_bf16(qf[1][ks], kf[ct], s[1][ct], 0, 0, 0);
      }
    }
    // ---- exp + den accumulate + P -> LDS buf[ch&1] (C layout) ----
    short* buf = plds + (ch & 1) * PBUF;
#pragma unroll
    for (int rt = 0; rt < 2; ++rt)
#pragma unroll
      for (int ct = 0; ct < 4; ++ct)
#pragma unroll
        for (int r = 0; r < 4; ++r) {
          float p = exp2f(s[rt][ct][r] * SCALE_LOG2E);
          den[rt][r] += p;
          buf[(rt * 16 + quad * 4 + r) * PPITCH + wave * 64 + ct * 16 + l15] = f2b(p);
        }
    __syncthreads();  // single barrier/chunk: dbuf covers read-vs-overwrite
    // ---- PV: this wave computes features wave*64..+63, K over 256 cols ------
#pragma unroll
    for (int ks = 0; ks < 8; ++ks) {
      int ko = ks * 32 + quad * 8;
      bf16x8 pa0 = *reinterpret_cast<const bf16x8*>(buf + l15 * PPITCH + ko);
      bf16x8 pa1 = *reinterpret_cast<const bf16x8*>(buf + (16 + l15) * PPITCH + ko);
#pragma unroll
      for (int ft = 0; ft < 4; ++ft) {
        int feat = wave * 64 + ft * 16 + l15;
        bf16x8 vb = *reinterpret_cast<const bf16x8*>(vt + (size_t)feat * NN + c0 + ko);
        acc[0][ft] = __builtin_amdgcn_mfma_f32_16x16x32_bf16(pa0, vb, acc[0][ft], 0, 0, 0);
        acc[1][ft] = __builtin_amdgcn_mfma_f32_16x16x32_bf16(pa1, vb, acc[1][ft], 0, 0, 0);
      }
    }
  }
  // ---- write partial num ----
  float* npB = nump + (size_t)q * NN * DQK;
#pragma unroll
  for (int rt = 0; rt < 2; ++rt)
#pragma unroll
    for (int ft = 0; ft < 4; ++ft) {
      int row = r0 + rt * 16 + quad * 4;
      int feat = wave * 64 + ft * 16 + l15;
#pragma unroll
      for (int r = 0; r < 4; ++r) npB[(size_t)(row + r) * DQK + feat] = acc[rt][ft][r];
    }
  // ---- reduce den across 16 lanes of quad, then across waves ----
#pragma unroll
  for (int rt = 0; rt < 2; ++rt)
#pragma unroll
    for (int r = 0; r < 4; ++r) {
      float d = den[rt][r];
      d += __shfl_xor(d, 1);
      d += __shfl_xor(d, 2);
      d += __shfl_xor(d, 4);
      d += __shfl_xor(d, 8);
      if (l15 == 0) dlds[wave][rt * 16 + quad * 4 + r] = d;
    }
  __syncthreads();
  if (tid < BM) {
    float d = dlds[0][tid] + dlds[1][tid] + dlds[2][tid] + dlds[3][tid];
    denp[q * NN + r0 + tid] = d;
  }
}

// ---------------- K6: per-row sparse correction + combine + normalize --------
__global__ __launch_bounds__(256) void k6_combine(
    const int* __restrict__ eidx, const float* __restrict__ bias,
    const float* __restrict__ es, const int* __restrict__ rowptr,
    const int* __restrict__ slot, const float* __restrict__ mag,
    const float* __restrict__ phase, const float* __restrict__ nump,
    const float* __restrict__ denp, float* __restrict__ out, int nsplit) {
  __shared__ int js[512];
  __shared__ float bs[512];
  __shared__ float ess[512];
  __shared__ int keepf[512];
  __shared__ f32x4 ncl[4][64];
  __shared__ float dcl[4];
  int i = blockIdx.x;
  int tid = threadIdx.x;
  int wave = tid >> 6;
  int lane = tid & 63;
  int start = rowptr[i];
  int cnt = rowptr[i + 1] - start;
  if (cnt > 512) cnt = 512;  // Poisson(32): unreachable in practice
  for (int p = tid; p < cnt; p += 256) {
    int eid = slot[start + p];
    js[p] = eidx[EE + eid];
    bs[p] = bias[eid];
    ess[p] = es[eid];
  }
  __syncthreads();
  // exact duplicate-(i,j) merge: first occurrence keeps summed beta
  {
    int myp[2];
    float mybsum[2];
    int mykeep[2];
    int nmine = 0;
    for (int p = tid; p < cnt; p += 256) {
      int j = js[p];
      float bsum = bs[p];
      int keep = 1;
      for (int qq = 0; qq < cnt; ++qq) {
        if (qq == p || js[qq] != j) continue;
        if (qq < p) { keep = 0; break; }
        bsum += bs[qq];
      }
      myp[nmine] = p; mybsum[nmine] = bsum; mykeep[nmine] = keep; ++nmine;
    }
    __syncthreads();
    for (int k = 0; k < nmine; ++k) { bs[myp[k]] = mybsum[k]; keepf[myp[k]] = mykeep[k]; }
    __syncthreads();
  }
  // edges split across 4 waves; lane f = 4*lane features of [mag|phase]
  const float* vbase = (lane < 32) ? (mag + 4 * lane) : (phase + 4 * lane - 128);
  f32x4 nc = {0.f, 0.f, 0.f, 0.f};
  float denc = 0.f;
  for (int p = wave; p < cnt; p += 4) {
    if (!keepf[p]) continue;
    float delta = ess[p] * expm1f(bs[p]);
    denc += delta;
    f32x4 v = *reinterpret_cast<const f32x4*>(vbase + (size_t)js[p] * DD);
    nc += delta * v;
  }
  ncl[wave][lane] = nc;
  if (lane == 0) dcl[wave] = denc;
  __syncthreads();
  if (wave == 0) {
    f32x4 nd = ncl[0][lane] + ncl[1][lane] + ncl[2][lane] + ncl[3][lane];
    float den = dcl[0] + dcl[1] + dcl[2] + dcl[3];
    for (int qq = 0; qq < nsplit; ++qq) {
      nd += *reinterpret_cast<const f32x4*>(nump + ((size_t)qq * NN + i) * DQK + 4 * lane);
      den += denp[qq * NN + i];
    }
    f32x4 res = nd * (1.0f / den);
    if (lane < 32)
      *reinterpret_cast<f32x4*>(out + (size_t)i * DD + 4 * lane) = res;
    else
      *reinterpret_cast<f32x4*>(out + (size_t)NN * DD + (size_t)i * DD + 4 * lane - 128) = res;
  }
}

// ---------------- workspace layout -------------------------------------------
constexpr size_t OFF_QK = 0;                                  // 4 MiB bf16
constexpr size_t OFF_VT = (size_t)NN * DQK * 2;               // 4 MiB bf16
constexpr size_t OFF_BIAS = OFF_VT + (size_t)DQK * NN * 2;    // 1 MiB f32
constexpr size_t OFF_ES = OFF_BIAS + (size_t)EE * 4;          // 1 MiB f32
constexpr size_t OFF_CNT = OFF_ES + (size_t)EE * 4;
constexpr size_t OFF_ROWPTR = OFF_CNT + (size_t)NN * 4;
constexpr size_t OFF_CURSOR = OFF_ROWPTR + (size_t)(NN + 2) * 4;
constexpr size_t OFF_SLOT = OFF_CURSOR + (size_t)NN * 4;
constexpr size_t OFF_NUMP = (OFF_SLOT + (size_t)EE * 4 + 255) & ~(size_t)255;
constexpr size_t WS_NEED4 = OFF_NUMP + 4ull * NN * DQK * 4 + 4ull * NN * 4;
constexpr size_t WS_NEED2 = OFF_NUMP + 2ull * NN * DQK * 4 + 2ull * NN * 4;

extern "C" void kernel_launch(void* const* d_in, const int* in_sizes, int n_in,
                              void* d_out, int out_size, void* d_ws, size_t ws_size,
                              hipStream_t stream) {
  const float* mag = (const float*)d_in[0];
  const float* phase = (const float*)d_in[1];
  const int* eidx = (const int*)d_in[2];
  const float* rbf = (const float*)d_in[3];
  const float* W1 = (const float*)d_in[4];
  const float* b1 = (const float*)d_in[5];
  const float* W2 = (const float*)d_in[6];
  const float* b2 = (const float*)d_in[7];
  float* out = (float*)d_out;
  char* ws = (char*)d_ws;
  if (ws_size < WS_NEED2) return;
  int nsplit = (ws_size >= WS_NEED4) ? 4 : 2;

  short* qkb = (short*)(ws + OFF_QK);
  short* vtb = (short*)(ws + OFF_VT);
  float* bias = (float*)(ws + OFF_BIAS);
  float* es = (float*)(ws + OFF_ES);
  int* cnt = (int*)(ws + OFF_CNT);
  int* rowptr = (int*)(ws + OFF_ROWPTR);
  int* cursor = (int*)(ws + OFF_CURSOR);
  int* slot = (int*)(ws + OFF_SLOT);
  float* nump = (float*)(ws + OFF_NUMP);
  float* denp = (float*)(ws + OFF_NUMP + (size_t)nsplit * NN * DQK * 4);

  hipMemsetAsync(cnt, 0, (size_t)NN * 4, stream);
  k1a_qk<<<NN * DD / 256, 256, 0, stream>>>(mag, phase, qkb);
  k1b_vt<<<dim3(NN / 64, DD / 64, 2), 256, 0, stream>>>(mag, phase, vtb);
  k2_mlp<<<EE / 256, 256, 0, stream>>>(rbf, W1, b1, W2, b2, eidx, bias, cnt);
  k3_scan<<<1, 1024, 0, stream>>>(cnt, rowptr, cursor);
  k4_scatter<<<EE / 256, 256, 0, stream>>>(eidx, cursor, slot);
  k45_dot<<<EE / 32, 256, 0, stream>>>(eidx, qkb, es);
  if (nsplit == 4)
    k5_flash<4><<<(NN / BM) * 4, 256, 0, stream>>>(qkb, vtb, nump, denp);
  else
    k5_flash<2><<<(NN / BM) * 2, 256, 0, stream>>>(qkb, vtb, nump, denp);
  k6_combine<<<NN, 256, 0, stream>>>(eidx, bias, es, rowptr, slot, mag, phase, nump,
                                     denp, out, nsplit);
}

// Round 4
// 352.141 us; speedup vs baseline: 1.6275x; 1.3783x over previous
//
#include <hip/hip_runtime.h>
#include <hip/hip_bf16.h>

#define NN 8192
#define DD 128
#define DQK 256
#define EE 262144
#define EDGE_DIM 50
#define HID 32
#define SCALE 0.08838834764831845f          // 1/sqrt(128)
#define SCALE_LOG2E 0.12752455522410585f    // SCALE * log2(e)

using f32x4 = __attribute__((ext_vector_type(4))) float;
using f32x2 = __attribute__((ext_vector_type(2))) float;
using bf16x8 = __attribute__((ext_vector_type(8))) short;  // 8 bf16 = 4 VGPRs
using s16x4 = __attribute__((ext_vector_type(4))) short;

static __device__ __forceinline__ short f2b(float f) {
  __hip_bfloat16 h = __float2bfloat16(f);
  return __builtin_bit_cast(short, h);
}
static __device__ __forceinline__ float b2f(short s) {
  unsigned u = ((unsigned)(unsigned short)s) << 16;
  return __builtin_bit_cast(float, u);
}

// ---------------- K1a: QK[n][0:128]=mag*cos, [128:256]=mag*sin (bf16) --------
__global__ void k1a_qk(const float* __restrict__ mag, const float* __restrict__ phase,
                       short* __restrict__ qkb) {
  int t = blockIdx.x * 256 + threadIdx.x;
  int n = t >> 7, d = t & 127;
  float m = mag[t], p = phase[t];
  float sn, cs;
  __sincosf(p, &sn, &cs);
  qkb[n * DQK + d] = f2b(m * cs);
  qkb[n * DQK + 128 + d] = f2b(m * sn);
}

// ---------------- K1b: VT[f][n] = V[n][f], V=[mag|phase], bf16 ---------------
__global__ void k1b_vt(const float* __restrict__ mag, const float* __restrict__ phase,
                       short* __restrict__ vtb) {
  __shared__ float tile[64][65];
  int bn = blockIdx.x, bd = blockIdx.y, sel = blockIdx.z;
  const float* src = sel ? phase : mag;
  int t = threadIdx.x;
#pragma unroll
  for (int rep = 0; rep < 16; ++rep) {
    int idx = rep * 256 + t;
    int r = idx >> 6, c = idx & 63;
    tile[r][c] = src[(size_t)(bn * 64 + r) * DD + bd * 64 + c];
  }
  __syncthreads();
#pragma unroll
  for (int rep = 0; rep < 16; ++rep) {
    int idx = rep * 256 + t;
    int r = idx >> 6, c = idx & 63;
    vtb[(size_t)(sel * 128 + bd * 64 + r) * NN + bn * 64 + c] = f2b(tile[c][r]);
  }
}

// ---------------- K2: edge MLP bias + row histogram --------------------------
__global__ __launch_bounds__(256) void k2_mlp(
    const float* __restrict__ rbf, const float* __restrict__ W1,
    const float* __restrict__ b1, const float* __restrict__ W2,
    const float* __restrict__ b2, const int* __restrict__ eidx,
    float* __restrict__ bias, int* __restrict__ cnt) {
  __shared__ alignas(16) float w1s[EDGE_DIM * HID];
  __shared__ alignas(16) float b1s[HID];
  __shared__ alignas(16) float w2s[HID];
  __shared__ float b2s;
  int tid = threadIdx.x;
  for (int k = tid; k < EDGE_DIM * HID; k += 256) w1s[k] = W1[k];
  if (tid < HID) { b1s[tid] = b1[tid]; w2s[tid] = W2[tid]; }
  if (tid == 0) b2s = b2[0];
  __syncthreads();
  int e = blockIdx.x * 256 + tid;
  const f32x2* r2 = reinterpret_cast<const f32x2*>(rbf + (size_t)e * EDGE_DIM);
  f32x2 rr[25];
#pragma unroll
  for (int k = 0; k < 25; ++k) rr[k] = r2[k];
  f32x4 h[8];
#pragma unroll
  for (int jj = 0; jj < 8; ++jj) h[jj] = reinterpret_cast<const f32x4*>(b1s)[jj];
#pragma unroll
  for (int k = 0; k < 25; ++k) {
    const f32x4* w0 = reinterpret_cast<const f32x4*>(w1s + (2 * k) * HID);
    const f32x4* w1r = reinterpret_cast<const f32x4*>(w1s + (2 * k + 1) * HID);
#pragma unroll
    for (int jj = 0; jj < 8; ++jj) h[jj] += rr[k].x * w0[jj] + rr[k].y * w1r[jj];
  }
  float outv = b2s;
#pragma unroll
  for (int jj = 0; jj < 8; ++jj) {
    f32x4 x = h[jj];
    f32x4 sl;
#pragma unroll
    for (int q = 0; q < 4; ++q) sl[q] = x[q] / (1.0f + __expf(-x[q]));
    f32x4 pr = sl * reinterpret_cast<const f32x4*>(w2s)[jj];
    outv += pr.x + pr.y + pr.z + pr.w;
  }
  bias[e] = outv;
  atomicAdd(&cnt[eidx[e]], 1);
}

// ---------------- K3: exclusive scan of counts -> rowptr, cursor -------------
__global__ __launch_bounds__(1024) void k3_scan(const int* __restrict__ cnt,
                                                int* __restrict__ rowptr,
                                                int* __restrict__ cursor) {
  __shared__ int sums[1024];
  int t = threadIdx.x;
  int v[8];
  int loc = 0;
#pragma unroll
  for (int k = 0; k < 8; ++k) { v[k] = cnt[t * 8 + k]; loc += v[k]; }
  sums[t] = loc;
  __syncthreads();
  for (int off = 1; off < 1024; off <<= 1) {
    int x = (t >= off) ? sums[t - off] : 0;
    __syncthreads();
    sums[t] += x;
    __syncthreads();
  }
  int excl = sums[t] - loc;
#pragma unroll
  for (int k = 0; k < 8; ++k) {
    rowptr[t * 8 + k] = excl;
    cursor[t * 8 + k] = excl;
    excl += v[k];
  }
  if (t == 1023) rowptr[NN] = excl;
}

// ---------------- K4: scatter edge ids into CSR slots ------------------------
__global__ void k4_scatter(const int* __restrict__ eidx, int* __restrict__ cursor,
                           int* __restrict__ slot) {
  int e = blockIdx.x * 256 + threadIdx.x;
  int i = eidx[e];
  int p = atomicAdd(&cursor[i], 1);
  slot[p] = e;
}

// ---------------- K45: per-edge exp(score) — 8 lanes per edge ----------------
__global__ __launch_bounds__(256) void k45_dot(const int* __restrict__ eidx,
                                               const short* __restrict__ qk,
                                               float* __restrict__ es) {
  int tid = threadIdx.x;
  int e = blockIdx.x * 32 + (tid >> 3);
  int sub = tid & 7;
  int i = eidx[e];
  int j = eidx[EE + e];
  const bf16x8* qa = reinterpret_cast<const bf16x8*>(qk + (size_t)i * DQK + sub * 32);
  const bf16x8* kb = reinterpret_cast<const bf16x8*>(qk + (size_t)j * DQK + sub * 32);
  float sp = 0.f;
#pragma unroll
  for (int t = 0; t < 4; ++t) {
    bf16x8 qa_v = qa[t];
    bf16x8 kb_v = kb[t];
#pragma unroll
    for (int u = 0; u < 8; ++u) sp += b2f(qa_v[u]) * b2f(kb_v[u]);
  }
  sp += __shfl_xor(sp, 1);
  sp += __shfl_xor(sp, 2);
  sp += __shfl_xor(sp, 4);
  if (sub == 0) es[e] = __expf(sp * SCALE);
}

// ---------------- K5: fused dense flash, LDS-staged (m97-style) --------------
// 512 threads = 8 waves (2 row x 4 col). BM=128 rows/block, BN=128-col chunks.
// Q-tile in LDS once; K-chunk double-buffered in LDS; P transits LDS; VT
// subtiles reuse the K buffer. All MFMA operands via ds_read_b128, padded
// pitches (+8 shorts -> row phase 4 banks -> only free 2-way conflicts).
constexpr int TBM = 128;
constexpr int TBN = 128;
constexpr int QP = 264;   // Qs pitch (shorts), 528 B rows
constexpr int KP = 72;    // Ks/VT pitch (shorts), 144 B rows
constexpr int PP = 136;   // P pitch (shorts), 272 B rows

template <int NSPLIT>
__global__ __launch_bounds__(512, 2) void k5_flash(
    const short* __restrict__ qk,  // [N][256] bf16
    const short* __restrict__ vt,  // [256][N] bf16
    float* __restrict__ nump,      // [NSPLIT][N][256]
    float* __restrict__ denp) {    // [NSPLIT][N]
  constexpr int QCOLS = NN / NSPLIT;
  constexpr int NCHUNK = QCOLS / TBN;
  constexpr int GPQ = 8 / NSPLIT;
  __shared__ short Qs[TBM * QP];       // 67584 B
  __shared__ short KV[2 * TBN * KP];   // 36864 B: K dbuf during QK, VT during PV
  __shared__ short Ps[TBM * PP];       // 34816 B
  __shared__ float dl[4][TBM];         // 2048 B
  int b = blockIdx.x;
  // XCD swizzle: same col-split q lands on a fixed XCD subset -> its 2 MB
  // K+VT slice stays L2-resident there.
  int q = (b & 7) / GPQ;
  int rb = (b >> 3) * GPQ + (b & (GPQ - 1));
  int tid = threadIdx.x;
  int w = tid >> 6, lane = tid & 63;
  int wr = w >> 2, wc = w & 3;
  int l15 = lane & 15, quad = lane >> 4;
  int r0 = rb * TBM;
  int cbase = q * QCOLS;

  // ---- stage Q tile once (coalesced: 32 lanes cover one 512-B row) ----
#pragma unroll
  for (int p = 0; p < 8; ++p) {
    int idx = p * 512 + tid;
    int row = idx >> 5, g = idx & 31;
    *(bf16x8*)&Qs[row * QP + g * 8] =
        *(const bf16x8*)(qk + (size_t)(r0 + row) * DQK + g * 8);
  }

  f32x4 o[4][4] = {};   // [rowtile][feattile] O-acc
  float den[4][4] = {}; // [rowtile][reg-row] partial denominators
  __syncthreads();

  for (int ch = 0; ch < NCHUNK; ++ch) {
    int c0 = cbase + ch * TBN;
    // ---- stage K bk=0 into buf0 ----
#pragma unroll
    for (int p = 0; p < 2; ++p) {
      int idx = p * 512 + tid;
      int col = idx >> 3, g = idx & 7;
      *(bf16x8*)&KV[col * KP + g * 8] =
          *(const bf16x8*)(qk + (size_t)(c0 + col) * DQK + g * 8);
    }
    __syncthreads();
    // ---- QK^T: S[128x128], K over 4 bk of 64 (double-buffered) ----
    f32x4 s[4][2] = {};
#pragma unroll
    for (int bk = 0; bk < 4; ++bk) {
      int buf = bk & 1;
      if (bk < 3) {
        int nb = buf ^ 1;
#pragma unroll
        for (int p = 0; p < 2; ++p) {
          int idx = p * 512 + tid;
          int col = idx >> 3, g = idx & 7;
          *(bf16x8*)&KV[nb * (TBN * KP) + col * KP + g * 8] =
              *(const bf16x8*)(qk + (size_t)(c0 + col) * DQK + (bk + 1) * 64 + g * 8);
        }
      }
#pragma unroll
      for (int ks = 0; ks < 2; ++ks) {
        int ko = ks * 32 + quad * 8;
        bf16x8 a[4], bb[2];
#pragma unroll
        for (int rt = 0; rt < 4; ++rt)
          a[rt] = *(const bf16x8*)&Qs[(wr * 64 + rt * 16 + l15) * QP + bk * 64 + ko];
#pragma unroll
        for (int ct = 0; ct < 2; ++ct)
          bb[ct] = *(const bf16x8*)&KV[buf * (TBN * KP) + (wc * 32 + ct * 16 + l15) * KP + ko];
#pragma unroll
        for (int rt = 0; rt < 4; ++rt)
#pragma unroll
          for (int ct = 0; ct < 2; ++ct)
            s[rt][ct] = __builtin_amdgcn_mfma_f32_16x16x32_bf16(a[rt], bb[ct],
                                                                s[rt][ct], 0, 0, 0);
      }
      __syncthreads();  // buf reads done (safe to overwrite next bk), writes visible
    }
    // ---- exp + P->LDS (C layout: row=quad*4+r, col=l15) + den ----
#pragma unroll
    for (int rt = 0; rt < 4; ++rt)
#pragma unroll
      for (int ct = 0; ct < 2; ++ct)
#pragma unroll
        for (int r = 0; r < 4; ++r) {
          float pv = exp2f(s[rt][ct][r] * SCALE_LOG2E);
          den[rt][r] += pv;
          Ps[(wr * 64 + rt * 16 + quad * 4 + r) * PP + wc * 32 + ct * 16 + l15] = f2b(pv);
        }
    __syncthreads();  // P visible; K reads done -> KV reusable as VT
    // ---- PV: O += P(128xj) x V(jx256), j in 2 subtiles of 64 ----
#pragma unroll
    for (int jb = 0; jb < 2; ++jb) {
#pragma unroll
      for (int p = 0; p < 4; ++p) {
        int idx = p * 512 + tid;
        int feat = idx >> 3, g = idx & 7;
        *(bf16x8*)&KV[feat * KP + g * 8] =
            *(const bf16x8*)(vt + (size_t)feat * NN + c0 + jb * 64 + g * 8);
      }
      __syncthreads();
#pragma unroll
      for (int ks = 0; ks < 2; ++ks) {
        int ko = ks * 32 + quad * 8;
        bf16x8 pa[4], vb[4];
#pragma unroll
        for (int rt = 0; rt < 4; ++rt)
          pa[rt] = *(const bf16x8*)&Ps[(wr * 64 + rt * 16 + l15) * PP + jb * 64 + ko];
#pragma unroll
        for (int ft = 0; ft < 4; ++ft)
          vb[ft] = *(const bf16x8*)&KV[(wc * 64 + ft * 16 + l15) * KP + ko];
#pragma unroll
        for (int rt = 0; rt < 4; ++rt)
#pragma unroll
          for (int ft = 0; ft < 4; ++ft)
            o[rt][ft] = __builtin_amdgcn_mfma_f32_16x16x32_bf16(pa[rt], vb[ft],
                                                                o[rt][ft], 0, 0, 0);
      }
      __syncthreads();  // VT reads done before overwrite (jb=1 / next chunk K)
    }
  }
  // ---- epilogue: write partial num ----
  float* npB = nump + (size_t)q * NN * DQK;
#pragma unroll
  for (int rt = 0; rt < 4; ++rt)
#pragma unroll
    for (int ft = 0; ft < 4; ++ft) {
      int row = r0 + wr * 64 + rt * 16 + quad * 4;
      int feat = wc * 64 + ft * 16 + l15;
#pragma unroll
      for (int r = 0; r < 4; ++r)
        npB[(size_t)(row + r) * DQK + feat] = o[rt][ft][r];
    }
  // ---- den: reduce l15 within quad, then across col-waves ----
#pragma unroll
  for (int rt = 0; rt < 4; ++rt)
#pragma unroll
    for (int r = 0; r < 4; ++r) {
      float d = den[rt][r];
      d += __shfl_xor(d, 1);
      d += __shfl_xor(d, 2);
      d += __shfl_xor(d, 4);
      d += __shfl_xor(d, 8);
      if (l15 == 0) dl[wc][wr * 64 + rt * 16 + quad * 4 + r] = d;
    }
  __syncthreads();
  if (tid < TBM) {
    float d = dl[0][tid] + dl[1][tid] + dl[2][tid] + dl[3][tid];
    denp[q * NN + r0 + tid] = d;
  }
}

// ---------------- K6: per-row sparse correction + combine + normalize --------
__global__ __launch_bounds__(256) void k6_combine(
    const int* __restrict__ eidx, const float* __restrict__ bias,
    const float* __restrict__ es, const int* __restrict__ rowptr,
    const int* __restrict__ slot, const float* __restrict__ mag,
    const float* __restrict__ phase, const float* __restrict__ nump,
    const float* __restrict__ denp, float* __restrict__ out, int nsplit) {
  __shared__ int js[512];
  __shared__ float bs[512];
  __shared__ float ess[512];
  __shared__ int keepf[512];
  __shared__ f32x4 ncl[4][64];
  __shared__ float dcl[4];
  int i = blockIdx.x;
  int tid = threadIdx.x;
  int wave = tid >> 6;
  int lane = tid & 63;
  int start = rowptr[i];
  int cnt = rowptr[i + 1] - start;
  if (cnt > 512) cnt = 512;  // Poisson(32): unreachable in practice
  for (int p = tid; p < cnt; p += 256) {
    int eid = slot[start + p];
    js[p] = eidx[EE + eid];
    bs[p] = bias[eid];
    ess[p] = es[eid];
  }
  __syncthreads();
  // exact duplicate-(i,j) merge: first occurrence keeps summed beta
  {
    int myp[2];
    float mybsum[2];
    int mykeep[2];
    int nmine = 0;
    for (int p = tid; p < cnt; p += 256) {
      int j = js[p];
      float bsum = bs[p];
      int keep = 1;
      for (int qq = 0; qq < cnt; ++qq) {
        if (qq == p || js[qq] != j) continue;
        if (qq < p) { keep = 0; break; }
        bsum += bs[qq];
      }
      myp[nmine] = p; mybsum[nmine] = bsum; mykeep[nmine] = keep; ++nmine;
    }
    __syncthreads();
    for (int k = 0; k < nmine; ++k) { bs[myp[k]] = mybsum[k]; keepf[myp[k]] = mykeep[k]; }
    __syncthreads();
  }
  // edges split across 4 waves; lane f = 4*lane features of [mag|phase]
  const float* vbase = (lane < 32) ? (mag + 4 * lane) : (phase + 4 * lane - 128);
  f32x4 nc = {0.f, 0.f, 0.f, 0.f};
  float denc = 0.f;
  for (int p = wave; p < cnt; p += 4) {
    if (!keepf[p]) continue;
    float delta = ess[p] * expm1f(bs[p]);
    denc += delta;
    f32x4 v = *reinterpret_cast<const f32x4*>(vbase + (size_t)js[p] * DD);
    nc += delta * v;
  }
  ncl[wave][lane] = nc;
  if (lane == 0) dcl[wave] = denc;
  __syncthreads();
  if (wave == 0) {
    f32x4 nd = ncl[0][lane] + ncl[1][lane] + ncl[2][lane] + ncl[3][lane];
    float den = dcl[0] + dcl[1] + dcl[2] + dcl[3];
    for (int qq = 0; qq < nsplit; ++qq) {
      nd += *reinterpret_cast<const f32x4*>(nump + ((size_t)qq * NN + i) * DQK + 4 * lane);
      den += denp[qq * NN + i];
    }
    f32x4 res = nd * (1.0f / den);
    if (lane < 32)
      *reinterpret_cast<f32x4*>(out + (size_t)i * DD + 4 * lane) = res;
    else
      *reinterpret_cast<f32x4*>(out + (size_t)NN * DD + (size_t)i * DD + 4 * lane - 128) = res;
  }
}

// ---------------- workspace layout -------------------------------------------
constexpr size_t OFF_QK = 0;                                  // 4 MiB bf16
constexpr size_t OFF_VT = (size_t)NN * DQK * 2;               // 4 MiB bf16
constexpr size_t OFF_BIAS = OFF_VT + (size_t)DQK * NN * 2;    // 1 MiB f32
constexpr size_t OFF_ES = OFF_BIAS + (size_t)EE * 4;          // 1 MiB f32
constexpr size_t OFF_CNT = OFF_ES + (size_t)EE * 4;
constexpr size_t OFF_ROWPTR = OFF_CNT + (size_t)NN * 4;
constexpr size_t OFF_CURSOR = OFF_ROWPTR + (size_t)(NN + 2) * 4;
constexpr size_t OFF_SLOT = OFF_CURSOR + (size_t)NN * 4;
constexpr size_t OFF_NUMP = (OFF_SLOT + (size_t)EE * 4 + 255) & ~(size_t)255;
constexpr size_t WS_NEED4 = OFF_NUMP + 4ull * NN * DQK * 4 + 4ull * NN * 4;
constexpr size_t WS_NEED2 = OFF_NUMP + 2ull * NN * DQK * 4 + 2ull * NN * 4;

extern "C" void kernel_launch(void* const* d_in, const int* in_sizes, int n_in,
                              void* d_out, int out_size, void* d_ws, size_t ws_size,
                              hipStream_t stream) {
  const float* mag = (const float*)d_in[0];
  const float* phase = (const float*)d_in[1];
  const int* eidx = (const int*)d_in[2];
  const float* rbf = (const float*)d_in[3];
  const float* W1 = (const float*)d_in[4];
  const float* b1 = (const float*)d_in[5];
  const float* W2 = (const float*)d_in[6];
  const float* b2 = (const float*)d_in[7];
  float* out = (float*)d_out;
  char* ws = (char*)d_ws;
  if (ws_size < WS_NEED2) return;
  int nsplit = (ws_size >= WS_NEED4) ? 4 : 2;

  short* qkb = (short*)(ws + OFF_QK);
  short* vtb = (short*)(ws + OFF_VT);
  float* bias = (float*)(ws + OFF_BIAS);
  float* es = (float*)(ws + OFF_ES);
  int* cnt = (int*)(ws + OFF_CNT);
  int* rowptr = (int*)(ws + OFF_ROWPTR);
  int* cursor = (int*)(ws + OFF_CURSOR);
  int* slot = (int*)(ws + OFF_SLOT);
  float* nump = (float*)(ws + OFF_NUMP);
  float* denp = (float*)(ws + OFF_NUMP + (size_t)nsplit * NN * DQK * 4);

  hipMemsetAsync(cnt, 0, (size_t)NN * 4, stream);
  k1a_qk<<<NN * DD / 256, 256, 0, stream>>>(mag, phase, qkb);
  k1b_vt<<<dim3(NN / 64, DD / 64, 2), 256, 0, stream>>>(mag, phase, vtb);
  k2_mlp<<<EE / 256, 256, 0, stream>>>(rbf, W1, b1, W2, b2, eidx, bias, cnt);
  k3_scan<<<1, 1024, 0, stream>>>(cnt, rowptr, cursor);
  k4_scatter<<<EE / 256, 256, 0, stream>>>(eidx, cursor, slot);
  k45_dot<<<EE / 32, 256, 0, stream>>>(eidx, qkb, es);
  if (nsplit == 4)
    k5_flash<4><<<(NN / TBM) * 4, 512, 0, stream>>>(qkb, vtb, nump, denp);
  else
    k5_flash<2><<<(NN / TBM) * 2, 512, 0, stream>>>(qkb, vtb, nump, denp);
  k6_combine<<<NN, 256, 0, stream>>>(eidx, bias, es, rowptr, slot, mag, phase, nump,
                                     denp, out, nsplit);
}

// Round 5
// 333.342 us; speedup vs baseline: 1.7193x; 1.0564x over previous
//
#include <hip/hip_runtime.h>
#include <hip/hip_bf16.h>

#define NN 8192
#define DD 128
#define DQK 256
#define EE 262144
#define EDGE_DIM 50
#define HID 32
#define CAP 96                               // per-row edge cap (Poisson(32))
#define SCALE 0.08838834764831845f          // 1/sqrt(128)
#define SCALE_LOG2E 0.12752455522410585f    // SCALE * log2(e)

using f32x4 = __attribute__((ext_vector_type(4))) float;
using f32x2 = __attribute__((ext_vector_type(2))) float;
using bf16x8 = __attribute__((ext_vector_type(8))) short;  // 8 bf16 = 4 VGPRs
using s16x4 = __attribute__((ext_vector_type(4))) short;

static __device__ __forceinline__ short f2b(float f) {
  __hip_bfloat16 h = __float2bfloat16(f);
  return __builtin_bit_cast(short, h);
}
static __device__ __forceinline__ float b2f(short s) {
  unsigned u = ((unsigned)(unsigned short)s) << 16;
  return __builtin_bit_cast(float, u);
}

// ---------------- K1: qkb build + vtb transpose + cnt zero (fused) -----------
// qkb[n][0:128]=mag*cos, [128:256]=mag*sin (bf16); vtb[f][n]=[mag|phase]^T.
__global__ __launch_bounds__(256) void k1_prep(const float* __restrict__ mag,
                                               const float* __restrict__ phase,
                                               short* __restrict__ qkb,
                                               short* __restrict__ vtb,
                                               int* __restrict__ cnt) {
  __shared__ float tm[64][133];  // pitch 133: (133n) % 32 = 5n -> only 2-way
  __shared__ float tp[64][133];
  int bn = blockIdx.x;  // rows bn*64..bn*64+63
  int tid = threadIdx.x;
  if (tid < 64) cnt[bn * 64 + tid] = 0;
#pragma unroll
  for (int rep = 0; rep < 32; ++rep) {
    int idx = rep * 256 + tid;
    int r = idx >> 7, c = idx & 127;
    float m = mag[(size_t)(bn * 64 + r) * DD + c];
    float ph = phase[(size_t)(bn * 64 + r) * DD + c];
    tm[r][c] = m;
    tp[r][c] = ph;
    float sn, cs;
    __sincosf(ph, &sn, &cs);
    qkb[(size_t)(bn * 64 + r) * DQK + c] = f2b(m * cs);
    qkb[(size_t)(bn * 64 + r) * DQK + 128 + c] = f2b(m * sn);
  }
  __syncthreads();
#pragma unroll
  for (int rep = 0; rep < 32; ++rep) {
    int idx = rep * 256 + tid;
    int f = idx >> 6, n = idx & 63;
    vtb[(size_t)f * NN + bn * 64 + n] = f2b(tm[n][f]);
    vtb[(size_t)(128 + f) * NN + bn * 64 + n] = f2b(tp[n][f]);
  }
}

// ---------------- K2: edge MLP bias + direct bucket scatter ------------------
__global__ __launch_bounds__(256) void k2_mlp(
    const float* __restrict__ rbf, const float* __restrict__ W1,
    const float* __restrict__ b1, const float* __restrict__ W2,
    const float* __restrict__ b2, const int* __restrict__ eidx,
    float* __restrict__ bias, int* __restrict__ cnt, int* __restrict__ slot) {
  __shared__ alignas(16) float w1s[EDGE_DIM * HID];
  __shared__ alignas(16) float b1s[HID];
  __shared__ alignas(16) float w2s[HID];
  __shared__ float b2s;
  int tid = threadIdx.x;
  for (int k = tid; k < EDGE_DIM * HID; k += 256) w1s[k] = W1[k];
  if (tid < HID) { b1s[tid] = b1[tid]; w2s[tid] = W2[tid]; }
  if (tid == 0) b2s = b2[0];
  __syncthreads();
  int e = blockIdx.x * 256 + tid;
  const f32x2* r2 = reinterpret_cast<const f32x2*>(rbf + (size_t)e * EDGE_DIM);
  f32x2 rr[25];
#pragma unroll
  for (int k = 0; k < 25; ++k) rr[k] = r2[k];
  f32x4 h[8];
#pragma unroll
  for (int jj = 0; jj < 8; ++jj) h[jj] = reinterpret_cast<const f32x4*>(b1s)[jj];
#pragma unroll
  for (int k = 0; k < 25; ++k) {
    const f32x4* w0 = reinterpret_cast<const f32x4*>(w1s + (2 * k) * HID);
    const f32x4* w1r = reinterpret_cast<const f32x4*>(w1s + (2 * k + 1) * HID);
#pragma unroll
    for (int jj = 0; jj < 8; ++jj) h[jj] += rr[k].x * w0[jj] + rr[k].y * w1r[jj];
  }
  float outv = b2s;
#pragma unroll
  for (int jj = 0; jj < 8; ++jj) {
    f32x4 x = h[jj];
    f32x4 sl;
#pragma unroll
    for (int q = 0; q < 4; ++q) sl[q] = x[q] / (1.0f + __expf(-x[q]));
    f32x4 pr = sl * reinterpret_cast<const f32x4*>(w2s)[jj];
    outv += pr.x + pr.y + pr.z + pr.w;
  }
  bias[e] = outv;
  int i = eidx[e];
  int p = atomicAdd(&cnt[i], 1);
  if (p < CAP) slot[i * CAP + p] = e;
}

// ---------------- K5: fused dense flash, LDS-staged (m97-style) --------------
// 512 threads = 8 waves (2 row x 4 col). BM=128 rows/block, BN=128-col chunks.
// Q-tile in LDS once; K-chunk double-buffered in LDS; P transits LDS; VT
// subtiles reuse the K buffer. All MFMA operands via ds_read_b128, padded
// pitches (+8 shorts -> row phase 4 banks -> only free 2-way conflicts).
constexpr int TBM = 128;
constexpr int TBN = 128;
constexpr int QP = 264;   // Qs pitch (shorts), 528 B rows
constexpr int KP = 72;    // Ks/VT pitch (shorts), 144 B rows
constexpr int PP = 136;   // P pitch (shorts), 272 B rows

template <int NSPLIT>
__global__ __launch_bounds__(512, 2) void k5_flash(
    const short* __restrict__ qk,  // [N][256] bf16
    const short* __restrict__ vt,  // [256][N] bf16
    float* __restrict__ nump,      // [NSPLIT][N][256]
    float* __restrict__ denp) {    // [NSPLIT][N]
  constexpr int QCOLS = NN / NSPLIT;
  constexpr int NCHUNK = QCOLS / TBN;
  constexpr int GPQ = 8 / NSPLIT;
  __shared__ short Qs[TBM * QP];       // 67584 B
  __shared__ short KV[2 * TBN * KP];   // 36864 B: K dbuf during QK, VT during PV
  __shared__ short Ps[TBM * PP];       // 34816 B
  __shared__ float dl[4][TBM];         // 2048 B
  int b = blockIdx.x;
  // XCD swizzle: same col-split q lands on a fixed XCD subset -> its 2 MB
  // K+VT slice stays L2-resident there.
  int q = (b & 7) / GPQ;
  int rb = (b >> 3) * GPQ + (b & (GPQ - 1));
  int tid = threadIdx.x;
  int w = tid >> 6, lane = tid & 63;
  int wr = w >> 2, wc = w & 3;
  int l15 = lane & 15, quad = lane >> 4;
  int r0 = rb * TBM;
  int cbase = q * QCOLS;

  // ---- stage Q tile once (coalesced: 32 lanes cover one 512-B row) ----
#pragma unroll
  for (int p = 0; p < 8; ++p) {
    int idx = p * 512 + tid;
    int row = idx >> 5, g = idx & 31;
    *(bf16x8*)&Qs[row * QP + g * 8] =
        *(const bf16x8*)(qk + (size_t)(r0 + row) * DQK + g * 8);
  }

  f32x4 o[4][4] = {};   // [rowtile][feattile] O-acc
  float den[4][4] = {}; // [rowtile][reg-row] partial denominators
  __syncthreads();

  for (int ch = 0; ch < NCHUNK; ++ch) {
    int c0 = cbase + ch * TBN;
    // ---- stage K bk=0 into buf0 ----
#pragma unroll
    for (int p = 0; p < 2; ++p) {
      int idx = p * 512 + tid;
      int col = idx >> 3, g = idx & 7;
      *(bf16x8*)&KV[col * KP + g * 8] =
          *(const bf16x8*)(qk + (size_t)(c0 + col) * DQK + g * 8);
    }
    __syncthreads();
    // ---- QK^T: S[128x128], K over 4 bk of 64 (double-buffered) ----
    f32x4 s[4][2] = {};
#pragma unroll
    for (int bk = 0; bk < 4; ++bk) {
      int buf = bk & 1;
      if (bk < 3) {
        int nb = buf ^ 1;
#pragma unroll
        for (int p = 0; p < 2; ++p) {
          int idx = p * 512 + tid;
          int col = idx >> 3, g = idx & 7;
          *(bf16x8*)&KV[nb * (TBN * KP) + col * KP + g * 8] =
              *(const bf16x8*)(qk + (size_t)(c0 + col) * DQK + (bk + 1) * 64 + g * 8);
        }
      }
#pragma unroll
      for (int ks = 0; ks < 2; ++ks) {
        int ko = ks * 32 + quad * 8;
        bf16x8 a[4], bb[2];
#pragma unroll
        for (int rt = 0; rt < 4; ++rt)
          a[rt] = *(const bf16x8*)&Qs[(wr * 64 + rt * 16 + l15) * QP + bk * 64 + ko];
#pragma unroll
        for (int ct = 0; ct < 2; ++ct)
          bb[ct] = *(const bf16x8*)&KV[buf * (TBN * KP) + (wc * 32 + ct * 16 + l15) * KP + ko];
#pragma unroll
        for (int rt = 0; rt < 4; ++rt)
#pragma unroll
          for (int ct = 0; ct < 2; ++ct)
            s[rt][ct] = __builtin_amdgcn_mfma_f32_16x16x32_bf16(a[rt], bb[ct],
                                                                s[rt][ct], 0, 0, 0);
      }
      __syncthreads();  // buf reads done (safe to overwrite next bk), writes visible
    }
    // ---- exp + P->LDS (C layout: row=quad*4+r, col=l15) + den ----
#pragma unroll
    for (int rt = 0; rt < 4; ++rt)
#pragma unroll
      for (int ct = 0; ct < 2; ++ct)
#pragma unroll
        for (int r = 0; r < 4; ++r) {
          float pv = exp2f(s[rt][ct][r] * SCALE_LOG2E);
          den[rt][r] += pv;
          Ps[(wr * 64 + rt * 16 + quad * 4 + r) * PP + wc * 32 + ct * 16 + l15] = f2b(pv);
        }
    __syncthreads();  // P visible; K reads done -> KV reusable as VT
    // ---- PV: O += P(128xj) x V(jx256), j in 2 subtiles of 64 ----
#pragma unroll
    for (int jb = 0; jb < 2; ++jb) {
#pragma unroll
      for (int p = 0; p < 4; ++p) {
        int idx = p * 512 + tid;
        int feat = idx >> 3, g = idx & 7;
        *(bf16x8*)&KV[feat * KP + g * 8] =
            *(const bf16x8*)(vt + (size_t)feat * NN + c0 + jb * 64 + g * 8);
      }
      __syncthreads();
#pragma unroll
      for (int ks = 0; ks < 2; ++ks) {
        int ko = ks * 32 + quad * 8;
        bf16x8 pa[4], vb[4];
#pragma unroll
        for (int rt = 0; rt < 4; ++rt)
          pa[rt] = *(const bf16x8*)&Ps[(wr * 64 + rt * 16 + l15) * PP + jb * 64 + ko];
#pragma unroll
        for (int ft = 0; ft < 4; ++ft)
          vb[ft] = *(const bf16x8*)&KV[(wc * 64 + ft * 16 + l15) * KP + ko];
#pragma unroll
        for (int rt = 0; rt < 4; ++rt)
#pragma unroll
          for (int ft = 0; ft < 4; ++ft)
            o[rt][ft] = __builtin_amdgcn_mfma_f32_16x16x32_bf16(pa[rt], vb[ft],
                                                                o[rt][ft], 0, 0, 0);
      }
      __syncthreads();  // VT reads done before overwrite (jb=1 / next chunk K)
    }
  }
  // ---- epilogue: write partial num ----
  float* npB = nump + (size_t)q * NN * DQK;
#pragma unroll
  for (int rt = 0; rt < 4; ++rt)
#pragma unroll
    for (int ft = 0; ft < 4; ++ft) {
      int row = r0 + wr * 64 + rt * 16 + quad * 4;
      int feat = wc * 64 + ft * 16 + l15;
#pragma unroll
      for (int r = 0; r < 4; ++r)
        npB[(size_t)(row + r) * DQK + feat] = o[rt][ft][r];
    }
  // ---- den: reduce l15 within quad, then across col-waves ----
#pragma unroll
  for (int rt = 0; rt < 4; ++rt)
#pragma unroll
    for (int r = 0; r < 4; ++r) {
      float d = den[rt][r];
      d += __shfl_xor(d, 1);
      d += __shfl_xor(d, 2);
      d += __shfl_xor(d, 4);
      d += __shfl_xor(d, 8);
      if (l15 == 0) dl[wc][wr * 64 + rt * 16 + quad * 4 + r] = d;
    }
  __syncthreads();
  if (tid < TBM) {
    float d = dl[0][tid] + dl[1][tid] + dl[2][tid] + dl[3][tid];
    denp[q * NN + r0 + tid] = d;
  }
}

// ---------------- K6: per-row edge dot + merge + correction + combine --------
__global__ __launch_bounds__(256) void k6_combine(
    const int* __restrict__ eidx, const float* __restrict__ bias,
    const int* __restrict__ cntArr, const int* __restrict__ slot,
    const short* __restrict__ qk, const float* __restrict__ mag,
    const float* __restrict__ phase, const float* __restrict__ nump,
    const float* __restrict__ denp, float* __restrict__ out, int nsplit) {
  __shared__ short qs[DQK];
  __shared__ int js[CAP];
  __shared__ float bs[CAP];
  __shared__ float ess[CAP];
  __shared__ int keepf[CAP];
  __shared__ f32x4 ncl[4][64];
  __shared__ float dcl[4];
  int i = blockIdx.x;
  int tid = threadIdx.x;
  int wave = tid >> 6;
  int lane = tid & 63;
  int cnt = cntArr[i];
  if (cnt > CAP) cnt = CAP;
  if (tid < DQK) qs[tid] = qk[(size_t)i * DQK + tid];
  for (int p = tid; p < cnt; p += 256) {
    int e = slot[i * CAP + p];
    js[p] = eidx[EE + e];
    bs[p] = bias[e];
  }
  __syncthreads();
  // ---- per-edge exp(score): 8 lanes per edge ----
  int sub = lane & 7;
  for (int p = wave * 8 + (lane >> 3); p < cnt; p += 32) {
    int j = js[p];
    const bf16x8* kb = reinterpret_cast<const bf16x8*>(qk + (size_t)j * DQK + sub * 32);
    const bf16x8* qa = reinterpret_cast<const bf16x8*>(qs + sub * 32);
    float sp = 0.f;
#pragma unroll
    for (int t = 0; t < 4; ++t) {
      bf16x8 qv = qa[t];
      bf16x8 kv = kb[t];
#pragma unroll
      for (int u = 0; u < 8; ++u) sp += b2f(qv[u]) * b2f(kv[u]);
    }
    sp += __shfl_xor(sp, 1);
    sp += __shfl_xor(sp, 2);
    sp += __shfl_xor(sp, 4);
    if (sub == 0) ess[p] = __expf(sp * SCALE);
  }
  __syncthreads();
  // ---- exact duplicate-(i,j) merge: first occurrence keeps summed beta ----
  {
    float bsum = 0.f;
    int keep = 0;
    if (tid < cnt) {
      int j = js[tid];
      bsum = bs[tid];
      keep = 1;
      for (int qq = 0; qq < cnt; ++qq) {
        if (qq == tid || js[qq] != j) continue;
        if (qq < tid) { keep = 0; break; }
        bsum += bs[qq];
      }
    }
    __syncthreads();
    if (tid < cnt) { bs[tid] = bsum; keepf[tid] = keep; }
    __syncthreads();
  }
  // ---- correction accumulation: edges split across 4 waves ----
  const float* vbase = (lane < 32) ? (mag + 4 * lane) : (phase + 4 * lane - 128);
  f32x4 nc = {0.f, 0.f, 0.f, 0.f};
  float denc = 0.f;
  for (int p = wave; p < cnt; p += 4) {
    if (!keepf[p]) continue;
    float delta = ess[p] * expm1f(bs[p]);
    denc += delta;
    f32x4 v = *reinterpret_cast<const f32x4*>(vbase + (size_t)js[p] * DD);
    nc += delta * v;
  }
  ncl[wave][lane] = nc;
  if (lane == 0) dcl[wave] = denc;
  __syncthreads();
  if (wave == 0) {
    f32x4 nd = ncl[0][lane] + ncl[1][lane] + ncl[2][lane] + ncl[3][lane];
    float den = dcl[0] + dcl[1] + dcl[2] + dcl[3];
    for (int qq = 0; qq < nsplit; ++qq) {
      nd += *reinterpret_cast<const f32x4*>(nump + ((size_t)qq * NN + i) * DQK + 4 * lane);
      den += denp[qq * NN + i];
    }
    f32x4 res = nd * (1.0f / den);
    if (lane < 32)
      *reinterpret_cast<f32x4*>(out + (size_t)i * DD + 4 * lane) = res;
    else
      *reinterpret_cast<f32x4*>(out + (size_t)NN * DD + (size_t)i * DD + 4 * lane - 128) = res;
  }
}

// ---------------- workspace layout -------------------------------------------
constexpr size_t OFF_QK = 0;                                  // 4 MiB bf16
constexpr size_t OFF_VT = (size_t)NN * DQK * 2;               // 4 MiB bf16
constexpr size_t OFF_BIAS = OFF_VT + (size_t)DQK * NN * 2;    // 1 MiB f32
constexpr size_t OFF_CNT = OFF_BIAS + (size_t)EE * 4;
constexpr size_t OFF_SLOT = OFF_CNT + (size_t)NN * 4;
constexpr size_t OFF_NUMP = (OFF_SLOT + (size_t)NN * CAP * 4 + 255) & ~(size_t)255;
constexpr size_t WS_NEED4 = OFF_NUMP + 4ull * NN * DQK * 4 + 4ull * NN * 4;
constexpr size_t WS_NEED2 = OFF_NUMP + 2ull * NN * DQK * 4 + 2ull * NN * 4;

extern "C" void kernel_launch(void* const* d_in, const int* in_sizes, int n_in,
                              void* d_out, int out_size, void* d_ws, size_t ws_size,
                              hipStream_t stream) {
  const float* mag = (const float*)d_in[0];
  const float* phase = (const float*)d_in[1];
  const int* eidx = (const int*)d_in[2];
  const float* rbf = (const float*)d_in[3];
  const float* W1 = (const float*)d_in[4];
  const float* b1 = (const float*)d_in[5];
  const float* W2 = (const float*)d_in[6];
  const float* b2 = (const float*)d_in[7];
  float* out = (float*)d_out;
  char* ws = (char*)d_ws;
  if (ws_size < WS_NEED2) return;
  int nsplit = (ws_size >= WS_NEED4) ? 4 : 2;

  short* qkb = (short*)(ws + OFF_QK);
  short* vtb = (short*)(ws + OFF_VT);
  float* bias = (float*)(ws + OFF_BIAS);
  int* cnt = (int*)(ws + OFF_CNT);
  int* slot = (int*)(ws + OFF_SLOT);
  float* nump = (float*)(ws + OFF_NUMP);
  float* denp = (float*)(ws + OFF_NUMP + (size_t)nsplit * NN * DQK * 4);

  k1_prep<<<NN / 64, 256, 0, stream>>>(mag, phase, qkb, vtb, cnt);
  k2_mlp<<<EE / 256, 256, 0, stream>>>(rbf, W1, b1, W2, b2, eidx, bias, cnt, slot);
  if (nsplit == 4)
    k5_flash<4><<<(NN / TBM) * 4, 512, 0, stream>>>(qkb, vtb, nump, denp);
  else
    k5_flash<2><<<(NN / TBM) * 2, 512, 0, stream>>>(qkb, vtb, nump, denp);
  k6_combine<<<NN, 256, 0, stream>>>(eidx, bias, cnt, slot, qkb, mag, phase, nump,
                                     denp, out, nsplit);
}

// Round 6
// 314.645 us; speedup vs baseline: 1.8215x; 1.0594x over previous
//
#include <hip/hip_runtime.h>
#include <hip/hip_bf16.h>

#define NN 8192
#define DD 128
#define DQK 256
#define EE 262144
#define EDGE_DIM 50
#define HID 32
#define CAP 96                               // per-row edge cap (Poisson(32))
#define SCALE 0.08838834764831845f          // 1/sqrt(128)
#define SCALE_LOG2E 0.12752455522410585f    // SCALE * log2(e)

using f32x4 = __attribute__((ext_vector_type(4))) float;
using f32x2 = __attribute__((ext_vector_type(2))) float;
using bf16x8 = __attribute__((ext_vector_type(8))) short;  // 8 bf16 = 4 VGPRs
using s16x4 = __attribute__((ext_vector_type(4))) short;

static __device__ __forceinline__ short f2b(float f) {
  __hip_bfloat16 h = __float2bfloat16(f);
  return __builtin_bit_cast(short, h);
}
static __device__ __forceinline__ float b2f(short s) {
  unsigned u = ((unsigned)(unsigned short)s) << 16;
  return __builtin_bit_cast(float, u);
}

// ---------------- K1: heterogeneous prep, one dispatch, 4640 blocks ----------
// blocks [0,4096):   qkb[n][0:128]=mag*cos, [128:256]=mag*sin (elementwise)
// blocks [4096,4608): vtb[f][n] transpose via 64x64 LDS tiles (R4-proven)
// blocks [4608,4640): cnt zeroing
__global__ __launch_bounds__(256) void k1_prep(const float* __restrict__ mag,
                                               const float* __restrict__ phase,
                                               short* __restrict__ qkb,
                                               short* __restrict__ vtb,
                                               int* __restrict__ cnt) {
  __shared__ float tile[64][65];
  int b = blockIdx.x;
  int tid = threadIdx.x;
  if (b < 4096) {
    int t = b * 256 + tid;  // 0..N*128-1
    int n = t >> 7, d = t & 127;
    float m = mag[t], p = phase[t];
    float sn, cs;
    __sincosf(p, &sn, &cs);
    qkb[(size_t)n * DQK + d] = f2b(m * cs);
    qkb[(size_t)n * DQK + 128 + d] = f2b(m * sn);
    return;
  }
  if (b < 4608) {
    int r = b - 4096;
    int bn = r & 127, bd = (r >> 7) & 1, sel = r >> 8;
    const float* src = sel ? phase : mag;
#pragma unroll
    for (int rep = 0; rep < 16; ++rep) {
      int idx = rep * 256 + tid;
      int rr = idx >> 6, c = idx & 63;
      tile[rr][c] = src[(size_t)(bn * 64 + rr) * DD + bd * 64 + c];
    }
    __syncthreads();
#pragma unroll
    for (int rep = 0; rep < 16; ++rep) {
      int idx = rep * 256 + tid;
      int rr = idx >> 6, c = idx & 63;
      vtb[(size_t)(sel * 128 + bd * 64 + rr) * NN + bn * 64 + c] = f2b(tile[c][rr]);
    }
    return;
  }
  int r = b - 4608;
  cnt[r * 256 + tid] = 0;
}

// ---------------- K2: edge MLP bias + direct bucket scatter ------------------
__global__ __launch_bounds__(256) void k2_mlp(
    const float* __restrict__ rbf, const float* __restrict__ W1,
    const float* __restrict__ b1, const float* __restrict__ W2,
    const float* __restrict__ b2, const int* __restrict__ eidx,
    float* __restrict__ bias, int* __restrict__ cnt, int* __restrict__ slot) {
  __shared__ alignas(16) float w1s[EDGE_DIM * HID];
  __shared__ alignas(16) float b1s[HID];
  __shared__ alignas(16) float w2s[HID];
  __shared__ float b2s;
  int tid = threadIdx.x;
  for (int k = tid; k < EDGE_DIM * HID; k += 256) w1s[k] = W1[k];
  if (tid < HID) { b1s[tid] = b1[tid]; w2s[tid] = W2[tid]; }
  if (tid == 0) b2s = b2[0];
  __syncthreads();
  int e = blockIdx.x * 256 + tid;
  const float* rrow = rbf + (size_t)e * EDGE_DIM;
  f32x4 r4[12];
#pragma unroll
  for (int k = 0; k < 12; ++k) r4[k] = *reinterpret_cast<const f32x4*>(rrow + 4 * k);
  f32x2 rt = *reinterpret_cast<const f32x2*>(rrow + 48);
  f32x4 h[8];
#pragma unroll
  for (int jj = 0; jj < 8; ++jj) h[jj] = reinterpret_cast<const f32x4*>(b1s)[jj];
#pragma unroll
  for (int k = 0; k < 12; ++k) {
#pragma unroll
    for (int qq = 0; qq < 4; ++qq) {
      const f32x4* wrow = reinterpret_cast<const f32x4*>(w1s + (4 * k + qq) * HID);
#pragma unroll
      for (int jj = 0; jj < 8; ++jj) h[jj] += r4[k][qq] * wrow[jj];
    }
  }
  {
    const f32x4* w48 = reinterpret_cast<const f32x4*>(w1s + 48 * HID);
    const f32x4* w49 = reinterpret_cast<const f32x4*>(w1s + 49 * HID);
#pragma unroll
    for (int jj = 0; jj < 8; ++jj) h[jj] += rt.x * w48[jj] + rt.y * w49[jj];
  }
  float outv = b2s;
#pragma unroll
  for (int jj = 0; jj < 8; ++jj) {
    f32x4 x = h[jj];
    f32x4 sl;
#pragma unroll
    for (int q = 0; q < 4; ++q) sl[q] = x[q] / (1.0f + __expf(-x[q]));
    f32x4 pr = sl * reinterpret_cast<const f32x4*>(w2s)[jj];
    outv += pr.x + pr.y + pr.z + pr.w;
  }
  bias[e] = outv;
  int i = eidx[e];
  int p = atomicAdd(&cnt[i], 1);
  if (p < CAP) slot[i * CAP + p] = e;
}

// ---------------- K5: fused dense flash, LDS-staged (m97-style) --------------
constexpr int TBM = 128;
constexpr int TBN = 128;
constexpr int QP = 264;   // Qs pitch (shorts), 528 B rows
constexpr int KP = 72;    // Ks/VT pitch (shorts), 144 B rows
constexpr int PP = 136;   // P pitch (shorts), 272 B rows

template <int NSPLIT>
__global__ __launch_bounds__(512, 2) void k5_flash(
    const short* __restrict__ qk,  // [N][256] bf16
    const short* __restrict__ vt,  // [256][N] bf16
    float* __restrict__ nump,      // [NSPLIT][N][256]
    float* __restrict__ denp) {    // [NSPLIT][N]
  constexpr int QCOLS = NN / NSPLIT;
  constexpr int NCHUNK = QCOLS / TBN;
  constexpr int GPQ = 8 / NSPLIT;
  __shared__ short Qs[TBM * QP];       // 67584 B
  __shared__ short KV[2 * TBN * KP];   // 36864 B: K dbuf during QK, VT during PV
  __shared__ short Ps[TBM * PP];       // 34816 B
  __shared__ float dl[4][TBM];         // 2048 B
  int b = blockIdx.x;
  int q = (b & 7) / GPQ;
  int rb = (b >> 3) * GPQ + (b & (GPQ - 1));
  int tid = threadIdx.x;
  int w = tid >> 6, lane = tid & 63;
  int wr = w >> 2, wc = w & 3;
  int l15 = lane & 15, quad = lane >> 4;
  int r0 = rb * TBM;
  int cbase = q * QCOLS;

#pragma unroll
  for (int p = 0; p < 8; ++p) {
    int idx = p * 512 + tid;
    int row = idx >> 5, g = idx & 31;
    *(bf16x8*)&Qs[row * QP + g * 8] =
        *(const bf16x8*)(qk + (size_t)(r0 + row) * DQK + g * 8);
  }

  f32x4 o[4][4] = {};
  float den[4][4] = {};
  __syncthreads();

  for (int ch = 0; ch < NCHUNK; ++ch) {
    int c0 = cbase + ch * TBN;
#pragma unroll
    for (int p = 0; p < 2; ++p) {
      int idx = p * 512 + tid;
      int col = idx >> 3, g = idx & 7;
      *(bf16x8*)&KV[col * KP + g * 8] =
          *(const bf16x8*)(qk + (size_t)(c0 + col) * DQK + g * 8);
    }
    __syncthreads();
    f32x4 s[4][2] = {};
#pragma unroll
    for (int bk = 0; bk < 4; ++bk) {
      int buf = bk & 1;
      if (bk < 3) {
        int nb = buf ^ 1;
#pragma unroll
        for (int p = 0; p < 2; ++p) {
          int idx = p * 512 + tid;
          int col = idx >> 3, g = idx & 7;
          *(bf16x8*)&KV[nb * (TBN * KP) + col * KP + g * 8] =
              *(const bf16x8*)(qk + (size_t)(c0 + col) * DQK + (bk + 1) * 64 + g * 8);
        }
      }
#pragma unroll
      for (int ks = 0; ks < 2; ++ks) {
        int ko = ks * 32 + quad * 8;
        bf16x8 a[4], bb[2];
#pragma unroll
        for (int rt = 0; rt < 4; ++rt)
          a[rt] = *(const bf16x8*)&Qs[(wr * 64 + rt * 16 + l15) * QP + bk * 64 + ko];
#pragma unroll
        for (int ct = 0; ct < 2; ++ct)
          bb[ct] = *(const bf16x8*)&KV[buf * (TBN * KP) + (wc * 32 + ct * 16 + l15) * KP + ko];
#pragma unroll
        for (int rt = 0; rt < 4; ++rt)
#pragma unroll
          for (int ct = 0; ct < 2; ++ct)
            s[rt][ct] = __builtin_amdgcn_mfma_f32_16x16x32_bf16(a[rt], bb[ct],
                                                                s[rt][ct], 0, 0, 0);
      }
      __syncthreads();
    }
#pragma unroll
    for (int rt = 0; rt < 4; ++rt)
#pragma unroll
      for (int ct = 0; ct < 2; ++ct)
#pragma unroll
        for (int r = 0; r < 4; ++r) {
          float pv = exp2f(s[rt][ct][r] * SCALE_LOG2E);
          den[rt][r] += pv;
          Ps[(wr * 64 + rt * 16 + quad * 4 + r) * PP + wc * 32 + ct * 16 + l15] = f2b(pv);
        }
    __syncthreads();
#pragma unroll
    for (int jb = 0; jb < 2; ++jb) {
#pragma unroll
      for (int p = 0; p < 4; ++p) {
        int idx = p * 512 + tid;
        int feat = idx >> 3, g = idx & 7;
        *(bf16x8*)&KV[feat * KP + g * 8] =
            *(const bf16x8*)(vt + (size_t)feat * NN + c0 + jb * 64 + g * 8);
      }
      __syncthreads();
#pragma unroll
      for (int ks = 0; ks < 2; ++ks) {
        int ko = ks * 32 + quad * 8;
        bf16x8 pa[4], vb[4];
#pragma unroll
        for (int rt = 0; rt < 4; ++rt)
          pa[rt] = *(const bf16x8*)&Ps[(wr * 64 + rt * 16 + l15) * PP + jb * 64 + ko];
#pragma unroll
        for (int ft = 0; ft < 4; ++ft)
          vb[ft] = *(const bf16x8*)&KV[(wc * 64 + ft * 16 + l15) * KP + ko];
#pragma unroll
        for (int rt = 0; rt < 4; ++rt)
#pragma unroll
          for (int ft = 0; ft < 4; ++ft)
            o[rt][ft] = __builtin_amdgcn_mfma_f32_16x16x32_bf16(pa[rt], vb[ft],
                                                                o[rt][ft], 0, 0, 0);
      }
      __syncthreads();
    }
  }
  float* npB = nump + (size_t)q * NN * DQK;
#pragma unroll
  for (int rt = 0; rt < 4; ++rt)
#pragma unroll
    for (int ft = 0; ft < 4; ++ft) {
      int row = r0 + wr * 64 + rt * 16 + quad * 4;
      int feat = wc * 64 + ft * 16 + l15;
#pragma unroll
      for (int r = 0; r < 4; ++r)
        npB[(size_t)(row + r) * DQK + feat] = o[rt][ft][r];
    }
#pragma unroll
  for (int rt = 0; rt < 4; ++rt)
#pragma unroll
    for (int r = 0; r < 4; ++r) {
      float d = den[rt][r];
      d += __shfl_xor(d, 1);
      d += __shfl_xor(d, 2);
      d += __shfl_xor(d, 4);
      d += __shfl_xor(d, 8);
      if (l15 == 0) dl[wc][wr * 64 + rt * 16 + quad * 4 + r] = d;
    }
  __syncthreads();
  if (tid < TBM) {
    float d = dl[0][tid] + dl[1][tid] + dl[2][tid] + dl[3][tid];
    denp[q * NN + r0 + tid] = d;
  }
}

// ---------------- K6: per-row edge dot + merge + correction + combine --------
__global__ __launch_bounds__(256) void k6_combine(
    const int* __restrict__ eidx, const float* __restrict__ bias,
    const int* __restrict__ cntArr, const int* __restrict__ slot,
    const short* __restrict__ qk, const float* __restrict__ mag,
    const float* __restrict__ phase, const float* __restrict__ nump,
    const float* __restrict__ denp, float* __restrict__ out, int nsplit) {
  __shared__ short qs[DQK];
  __shared__ int js[CAP];
  __shared__ float bs[CAP];
  __shared__ float ess[CAP];
  __shared__ int keepf[CAP];
  __shared__ f32x4 ncl[4][64];
  __shared__ float dcl[4];
  int i = blockIdx.x;
  int tid = threadIdx.x;
  int wave = tid >> 6;
  int lane = tid & 63;
  int cnt = cntArr[i];
  if (cnt > CAP) cnt = CAP;
  if (tid < DQK) qs[tid] = qk[(size_t)i * DQK + tid];
  for (int p = tid; p < cnt; p += 256) {
    int e = slot[i * CAP + p];
    js[p] = eidx[EE + e];
    bs[p] = bias[e];
  }
  __syncthreads();
  // ---- per-edge exp(score): 8 lanes per edge ----
  int sub = lane & 7;
  for (int p = wave * 8 + (lane >> 3); p < cnt; p += 32) {
    int j = js[p];
    const bf16x8* kb = reinterpret_cast<const bf16x8*>(qk + (size_t)j * DQK + sub * 32);
    const bf16x8* qa = reinterpret_cast<const bf16x8*>(qs + sub * 32);
    float sp = 0.f;
#pragma unroll
    for (int t = 0; t < 4; ++t) {
      bf16x8 qv = qa[t];
      bf16x8 kv = kb[t];
#pragma unroll
      for (int u = 0; u < 8; ++u) sp += b2f(qv[u]) * b2f(kv[u]);
    }
    sp += __shfl_xor(sp, 1);
    sp += __shfl_xor(sp, 2);
    sp += __shfl_xor(sp, 4);
    if (sub == 0) ess[p] = __expf(sp * SCALE);
  }
  __syncthreads();
  // ---- exact duplicate-(i,j) merge ----
  {
    float bsum = 0.f;
    int keep = 0;
    if (tid < cnt) {
      int j = js[tid];
      bsum = bs[tid];
      keep = 1;
      for (int qq = 0; qq < cnt; ++qq) {
        if (qq == tid || js[qq] != j) continue;
        if (qq < tid) { keep = 0; break; }
        bsum += bs[qq];
      }
    }
    __syncthreads();
    if (tid < cnt) { bs[tid] = bsum; keepf[tid] = keep; }
    __syncthreads();
  }
  // ---- correction accumulation + per-wave dense-split partials ----
  const float* vbase = (lane < 32) ? (mag + 4 * lane) : (phase + 4 * lane - 128);
  f32x4 nc = {0.f, 0.f, 0.f, 0.f};
  float denc = 0.f;
  if (wave < nsplit) {
    nc = *reinterpret_cast<const f32x4*>(nump + ((size_t)wave * NN + i) * DQK + 4 * lane);
    if (lane == 0) denc = denp[wave * NN + i];
  }
  for (int p = wave; p < cnt; p += 4) {
    if (!keepf[p]) continue;
    float delta = ess[p] * expm1f(bs[p]);
    denc += delta;
    f32x4 v = *reinterpret_cast<const f32x4*>(vbase + (size_t)js[p] * DD);
    nc += delta * v;
  }
  ncl[wave][lane] = nc;
  if (lane == 0) dcl[wave] = denc;
  __syncthreads();
  if (wave == 0) {
    f32x4 nd = ncl[0][lane] + ncl[1][lane] + ncl[2][lane] + ncl[3][lane];
    float den = dcl[0] + dcl[1] + dcl[2] + dcl[3];
    f32x4 res = nd * (1.0f / den);
    if (lane < 32)
      *reinterpret_cast<f32x4*>(out + (size_t)i * DD + 4 * lane) = res;
    else
      *reinterpret_cast<f32x4*>(out + (size_t)NN * DD + (size_t)i * DD + 4 * lane - 128) = res;
  }
}

// ---------------- workspace layout -------------------------------------------
constexpr size_t OFF_QK = 0;                                  // 4 MiB bf16
constexpr size_t OFF_VT = (size_t)NN * DQK * 2;               // 4 MiB bf16
constexpr size_t OFF_BIAS = OFF_VT + (size_t)DQK * NN * 2;    // 1 MiB f32
constexpr size_t OFF_CNT = OFF_BIAS + (size_t)EE * 4;
constexpr size_t OFF_SLOT = OFF_CNT + (size_t)NN * 4;
constexpr size_t OFF_NUMP = (OFF_SLOT + (size_t)NN * CAP * 4 + 255) & ~(size_t)255;
constexpr size_t WS_NEED4 = OFF_NUMP + 4ull * NN * DQK * 4 + 4ull * NN * 4;
constexpr size_t WS_NEED2 = OFF_NUMP + 2ull * NN * DQK * 4 + 2ull * NN * 4;

extern "C" void kernel_launch(void* const* d_in, const int* in_sizes, int n_in,
                              void* d_out, int out_size, void* d_ws, size_t ws_size,
                              hipStream_t stream) {
  const float* mag = (const float*)d_in[0];
  const float* phase = (const float*)d_in[1];
  const int* eidx = (const int*)d_in[2];
  const float* rbf = (const float*)d_in[3];
  const float* W1 = (const float*)d_in[4];
  const float* b1 = (const float*)d_in[5];
  const float* W2 = (const float*)d_in[6];
  const float* b2 = (const float*)d_in[7];
  float* out = (float*)d_out;
  char* ws = (char*)d_ws;
  if (ws_size < WS_NEED2) return;
  int nsplit = (ws_size >= WS_NEED4) ? 4 : 2;

  short* qkb = (short*)(ws + OFF_QK);
  short* vtb = (short*)(ws + OFF_VT);
  float* bias = (float*)(ws + OFF_BIAS);
  int* cnt = (int*)(ws + OFF_CNT);
  int* slot = (int*)(ws + OFF_SLOT);
  float* nump = (float*)(ws + OFF_NUMP);
  float* denp = (float*)(ws + OFF_NUMP + (size_t)nsplit * NN * DQK * 4);

  k1_prep<<<4640, 256, 0, stream>>>(mag, phase, qkb, vtb, cnt);
  k2_mlp<<<EE / 256, 256, 0, stream>>>(rbf, W1, b1, W2, b2, eidx, bias, cnt, slot);
  if (nsplit == 4)
    k5_flash<4><<<(NN / TBM) * 4, 512, 0, stream>>>(qkb, vtb, nump, denp);
  else
    k5_flash<2><<<(NN / TBM) * 2, 512, 0, stream>>>(qkb, vtb, nump, denp);
  k6_combine<<<NN, 256, 0, stream>>>(eidx, bias, cnt, slot, qkb, mag, phase, nump,
                                     denp, out, nsplit);
}

// Round 7
// 304.799 us; speedup vs baseline: 1.8803x; 1.0323x over previous
//
#include <hip/hip_runtime.h>
#include <hip/hip_bf16.h>

#define NN 8192
#define DD 128
#define DQK 256
#define EE 262144
#define EDGE_DIM 50
#define HID 32
#define CAP 96                               // per-row edge cap (Poisson(32))
#define SCALE 0.08838834764831845f          // 1/sqrt(128)
#define SCALE_LOG2E 0.12752455522410585f    // SCALE * log2(e)

using f32x4 = __attribute__((ext_vector_type(4))) float;
using f32x2 = __attribute__((ext_vector_type(2))) float;
using bf16x8 = __attribute__((ext_vector_type(8))) short;  // 8 bf16 = 4 VGPRs
using s16x4 = __attribute__((ext_vector_type(4))) short;

static __device__ __forceinline__ short f2b(float f) {
  __hip_bfloat16 h = __float2bfloat16(f);
  return __builtin_bit_cast(short, h);
}
static __device__ __forceinline__ float b2f(short s) {
  unsigned u = ((unsigned)(unsigned short)s) << 16;
  return __builtin_bit_cast(float, u);
}
// async global->LDS, 16B per lane; lds dest = wave-uniform base + lane*16
static __device__ __forceinline__ void gll(const short* g, short* l) {
  __builtin_amdgcn_global_load_lds(
      (const __attribute__((address_space(1))) void*)g,
      (__attribute__((address_space(3))) void*)l, 16, 0, 0);
}

// ---------------- K1: heterogeneous prep + MLP, one dispatch -----------------
// blocks [0,4096):    qkb[n][0:128]=mag*cos, [128:256]=mag*sin (elementwise)
// blocks [4096,4608): vtb[f][n] transpose via 64x64 LDS tiles
// blocks [4608,5632): edge MLP bias + bucket scatter (cnt pre-zeroed by memset)
__global__ __launch_bounds__(256) void k1_mega(
    const float* __restrict__ mag, const float* __restrict__ phase,
    short* __restrict__ qkb, short* __restrict__ vtb,
    const float* __restrict__ rbf, const float* __restrict__ W1,
    const float* __restrict__ b1, const float* __restrict__ W2,
    const float* __restrict__ b2, const int* __restrict__ eidx,
    float* __restrict__ bias, int* __restrict__ cnt, int* __restrict__ slot) {
  __shared__ float tile[64][65];
  __shared__ alignas(16) float w1s[EDGE_DIM * HID];
  __shared__ alignas(16) float b1s[HID];
  __shared__ alignas(16) float w2s[HID];
  __shared__ float b2s;
  int b = blockIdx.x;
  int tid = threadIdx.x;
  if (b < 4096) {
    int t = b * 256 + tid;
    int n = t >> 7, d = t & 127;
    float m = mag[t], p = phase[t];
    float sn, cs;
    __sincosf(p, &sn, &cs);
    qkb[(size_t)n * DQK + d] = f2b(m * cs);
    qkb[(size_t)n * DQK + 128 + d] = f2b(m * sn);
    return;
  }
  if (b < 4608) {
    int r = b - 4096;
    int bn = r & 127, bd = (r >> 7) & 1, sel = r >> 8;
    const float* src = sel ? phase : mag;
#pragma unroll
    for (int rep = 0; rep < 16; ++rep) {
      int idx = rep * 256 + tid;
      int rr = idx >> 6, c = idx & 63;
      tile[rr][c] = src[(size_t)(bn * 64 + rr) * DD + bd * 64 + c];
    }
    __syncthreads();
#pragma unroll
    for (int rep = 0; rep < 16; ++rep) {
      int idx = rep * 256 + tid;
      int rr = idx >> 6, c = idx & 63;
      vtb[(size_t)(sel * 128 + bd * 64 + rr) * NN + bn * 64 + c] = f2b(tile[c][rr]);
    }
    return;
  }
  // ---- MLP branch ----
  for (int k = tid; k < EDGE_DIM * HID; k += 256) w1s[k] = W1[k];
  if (tid < HID) { b1s[tid] = b1[tid]; w2s[tid] = W2[tid]; }
  if (tid == 0) b2s = b2[0];
  __syncthreads();
  int e = (b - 4608) * 256 + tid;
  const float* rrow = rbf + (size_t)e * EDGE_DIM;
  f32x4 r4[12];
#pragma unroll
  for (int k = 0; k < 12; ++k) r4[k] = *reinterpret_cast<const f32x4*>(rrow + 4 * k);
  f32x2 rt2 = *reinterpret_cast<const f32x2*>(rrow + 48);
  f32x4 h[8];
#pragma unroll
  for (int jj = 0; jj < 8; ++jj) h[jj] = reinterpret_cast<const f32x4*>(b1s)[jj];
#pragma unroll
  for (int k = 0; k < 12; ++k) {
#pragma unroll
    for (int qq = 0; qq < 4; ++qq) {
      const f32x4* wrow = reinterpret_cast<const f32x4*>(w1s + (4 * k + qq) * HID);
#pragma unroll
      for (int jj = 0; jj < 8; ++jj) h[jj] += r4[k][qq] * wrow[jj];
    }
  }
  {
    const f32x4* w48 = reinterpret_cast<const f32x4*>(w1s + 48 * HID);
    const f32x4* w49 = reinterpret_cast<const f32x4*>(w1s + 49 * HID);
#pragma unroll
    for (int jj = 0; jj < 8; ++jj) h[jj] += rt2.x * w48[jj] + rt2.y * w49[jj];
  }
  float outv = b2s;
#pragma unroll
  for (int jj = 0; jj < 8; ++jj) {
    f32x4 x = h[jj];
    f32x4 sl;
#pragma unroll
    for (int q = 0; q < 4; ++q) sl[q] = x[q] / (1.0f + __expf(-x[q]));
    f32x4 pr = sl * reinterpret_cast<const f32x4*>(w2s)[jj];
    outv += pr.x + pr.y + pr.z + pr.w;
  }
  bias[e] = outv;
  int i = eidx[e];
  int p = atomicAdd(&cnt[i], 1);
  if (p < CAP) slot[i * CAP + p] = e;
}

// ---------------- K5: fused dense flash, global_load_lds staging -------------
// 512 threads = 8 waves (2 row x 4 col). Q[128x256], K slices [128x64] dbuf,
// V subtiles [256x64] reuse KV. Unpadded layouts + XOR group swizzle
// (grp ^= row&7): staging dests are lane-linear (global_load_lds constraint),
// fragment reads land 2 lanes/bank (free per m136).
constexpr int TBM = 128;
constexpr int TBN = 128;
constexpr int PP = 136;  // Ps pitch (shorts): reg-sourced, keeps padded layout

template <int NSPLIT>
__global__ __launch_bounds__(512, 2) void k5_flash(
    const short* __restrict__ qk,  // [N][256] bf16
    const short* __restrict__ vt,  // [256][N] bf16
    float* __restrict__ nump,      // [NSPLIT][N][256]
    float* __restrict__ denp) {    // [NSPLIT][N]
  constexpr int QCOLS = NN / NSPLIT;
  constexpr int NCHUNK = QCOLS / TBN;
  constexpr int GPQ = 8 / NSPLIT;
  __shared__ short Qs[TBM * 256];     // 64 KiB, swizzled
  __shared__ short KV[2 * TBN * 64];  // 32 KiB: K dbuf / V subtile, swizzled
  __shared__ short Ps[TBM * PP];      // 34 KiB
  __shared__ float dl[4][TBM];        // 2 KiB
  int b = blockIdx.x;
  int q = (b & 7) / GPQ;
  int rb = (b >> 3) * GPQ + (b & (GPQ - 1));
  int tid = threadIdx.x;
  int w = tid >> 6, lane = tid & 63;
  int wr = w >> 2, wc = w & 3;
  int l15 = lane & 15, quad = lane >> 4;
  int rsw = l15 & 7;  // read-side swizzle key (row&7 == l15&7 for all frags)
  int wbase = w * 64; // lane-linear staging base per wave
  int r0 = rb * TBM;
  int cbase = q * QCOLS;

  // ---- stage Q tile once: 8 passes x 8KB, direct to LDS ----
#pragma unroll
  for (int p = 0; p < 8; ++p) {
    int idx = p * 512 + tid;
    int row = idx >> 5, gs = idx & 31;
    gll(qk + (size_t)(r0 + row) * DQK + ((gs ^ (row & 7)) * 8),
        &Qs[(p * 512 + wbase) * 8]);
  }

  f32x4 o[4][4] = {};
  float den[4][4] = {};
  __syncthreads();

  for (int ch = 0; ch < NCHUNK; ++ch) {
    int c0 = cbase + ch * TBN;
    // ---- stage K slice bk=0 into buf0 ----
#pragma unroll
    for (int p = 0; p < 2; ++p) {
      int idx = p * 512 + tid;
      int col = idx >> 3, gs = idx & 7;
      gll(qk + (size_t)(c0 + col) * DQK + ((gs ^ (col & 7)) * 8),
          &KV[(p * 512 + wbase) * 8]);
    }
    __syncthreads();
    f32x4 s[4][2] = {};
#pragma unroll
    for (int bk = 0; bk < 4; ++bk) {
      int buf = bk & 1;
      if (bk < 3) {
        int nb = buf ^ 1;
#pragma unroll
        for (int p = 0; p < 2; ++p) {
          int idx = p * 512 + tid;
          int col = idx >> 3, gs = idx & 7;
          gll(qk + (size_t)(c0 + col) * DQK + (bk + 1) * 64 + ((gs ^ (col & 7)) * 8),
              &KV[nb * 8192 + (p * 512 + wbase) * 8]);
        }
      }
#pragma unroll
      for (int ks = 0; ks < 2; ++ks) {
        int g = ks * 4 + quad;
        bf16x8 a[4], bb[2];
#pragma unroll
        for (int rt = 0; rt < 4; ++rt)
          a[rt] = *(const bf16x8*)&Qs[(wr * 64 + rt * 16 + l15) * 256 +
                                      ((bk * 8 + g) ^ rsw) * 8];
#pragma unroll
        for (int ct = 0; ct < 2; ++ct)
          bb[ct] = *(const bf16x8*)&KV[buf * 8192 + (wc * 32 + ct * 16 + l15) * 64 +
                                       (g ^ rsw) * 8];
#pragma unroll
        for (int rt = 0; rt < 4; ++rt)
#pragma unroll
          for (int ct = 0; ct < 2; ++ct)
            s[rt][ct] = __builtin_amdgcn_mfma_f32_16x16x32_bf16(a[rt], bb[ct],
                                                                s[rt][ct], 0, 0, 0);
      }
      __syncthreads();
    }
    // ---- exp + P->LDS (C layout) + den ----
#pragma unroll
    for (int rt = 0; rt < 4; ++rt)
#pragma unroll
      for (int ct = 0; ct < 2; ++ct)
#pragma unroll
        for (int r = 0; r < 4; ++r) {
          float pv = exp2f(s[rt][ct][r] * SCALE_LOG2E);
          den[rt][r] += pv;
          Ps[(wr * 64 + rt * 16 + quad * 4 + r) * PP + wc * 32 + ct * 16 + l15] = f2b(pv);
        }
    __syncthreads();
    // ---- PV: V subtiles of 64 cols, staged direct to LDS ----
#pragma unroll
    for (int jb = 0; jb < 2; ++jb) {
#pragma unroll
      for (int p = 0; p < 4; ++p) {
        int idx = p * 512 + tid;
        int feat = idx >> 3, gs = idx & 7;
        gll(vt + (size_t)feat * NN + c0 + jb * 64 + ((gs ^ (feat & 7)) * 8),
            &KV[(p * 512 + wbase) * 8]);
      }
      __syncthreads();
#pragma unroll
      for (int ks = 0; ks < 2; ++ks) {
        int g = ks * 4 + quad;
        int ko = ks * 32 + quad * 8;
        bf16x8 pa[4], vb[4];
#pragma unroll
        for (int rt = 0; rt < 4; ++rt)
          pa[rt] = *(const bf16x8*)&Ps[(wr * 64 + rt * 16 + l15) * PP + jb * 64 + ko];
#pragma unroll
        for (int ft = 0; ft < 4; ++ft)
          vb[ft] = *(const bf16x8*)&KV[(wc * 64 + ft * 16 + l15) * 64 + (g ^ rsw) * 8];
#pragma unroll
        for (int rt = 0; rt < 4; ++rt)
#pragma unroll
          for (int ft = 0; ft < 4; ++ft)
            o[rt][ft] = __builtin_amdgcn_mfma_f32_16x16x32_bf16(pa[rt], vb[ft],
                                                                o[rt][ft], 0, 0, 0);
      }
      __syncthreads();
    }
  }
  float* npB = nump + (size_t)q * NN * DQK;
#pragma unroll
  for (int rt = 0; rt < 4; ++rt)
#pragma unroll
    for (int ft = 0; ft < 4; ++ft) {
      int row = r0 + wr * 64 + rt * 16 + quad * 4;
      int feat = wc * 64 + ft * 16 + l15;
#pragma unroll
      for (int r = 0; r < 4; ++r)
        npB[(size_t)(row + r) * DQK + feat] = o[rt][ft][r];
    }
#pragma unroll
  for (int rt = 0; rt < 4; ++rt)
#pragma unroll
    for (int r = 0; r < 4; ++r) {
      float d = den[rt][r];
      d += __shfl_xor(d, 1);
      d += __shfl_xor(d, 2);
      d += __shfl_xor(d, 4);
      d += __shfl_xor(d, 8);
      if (l15 == 0) dl[wc][wr * 64 + rt * 16 + quad * 4 + r] = d;
    }
  __syncthreads();
  if (tid < TBM) {
    float d = dl[0][tid] + dl[1][tid] + dl[2][tid] + dl[3][tid];
    denp[q * NN + r0 + tid] = d;
  }
}

// ---------------- K6: per-row edge dot + merge + correction + combine --------
__global__ __launch_bounds__(256) void k6_combine(
    const int* __restrict__ eidx, const float* __restrict__ bias,
    const int* __restrict__ cntArr, const int* __restrict__ slot,
    const short* __restrict__ qk, const float* __restrict__ mag,
    const float* __restrict__ phase, const float* __restrict__ nump,
    const float* __restrict__ denp, float* __restrict__ out, int nsplit) {
  __shared__ short qs[DQK];
  __shared__ int js[CAP];
  __shared__ float bs[CAP];
  __shared__ float ess[CAP];
  __shared__ int keepf[CAP];
  __shared__ f32x4 ncl[4][64];
  __shared__ float dcl[4];
  int i = blockIdx.x;
  int tid = threadIdx.x;
  int wave = tid >> 6;
  int lane = tid & 63;
  int cnt = cntArr[i];
  if (cnt > CAP) cnt = CAP;
  if (tid < DQK) qs[tid] = qk[(size_t)i * DQK + tid];
  for (int p = tid; p < cnt; p += 256) {
    int e = slot[i * CAP + p];
    js[p] = eidx[EE + e];
    bs[p] = bias[e];
  }
  __syncthreads();
  int sub = lane & 7;
  for (int p = wave * 8 + (lane >> 3); p < cnt; p += 32) {
    int j = js[p];
    const bf16x8* kb = reinterpret_cast<const bf16x8*>(qk + (size_t)j * DQK + sub * 32);
    const bf16x8* qa = reinterpret_cast<const bf16x8*>(qs + sub * 32);
    float sp = 0.f;
#pragma unroll
    for (int t = 0; t < 4; ++t) {
      bf16x8 qv = qa[t];
      bf16x8 kv = kb[t];
#pragma unroll
      for (int u = 0; u < 8; ++u) sp += b2f(qv[u]) * b2f(kv[u]);
    }
    sp += __shfl_xor(sp, 1);
    sp += __shfl_xor(sp, 2);
    sp += __shfl_xor(sp, 4);
    if (sub == 0) ess[p] = __expf(sp * SCALE);
  }
  __syncthreads();
  {
    float bsum = 0.f;
    int keep = 0;
    if (tid < cnt) {
      int j = js[tid];
      bsum = bs[tid];
      keep = 1;
      for (int qq = 0; qq < cnt; ++qq) {
        if (qq == tid || js[qq] != j) continue;
        if (qq < tid) { keep = 0; break; }
        bsum += bs[qq];
      }
    }
    __syncthreads();
    if (tid < cnt) { bs[tid] = bsum; keepf[tid] = keep; }
    __syncthreads();
  }
  const float* vbase = (lane < 32) ? (mag + 4 * lane) : (phase + 4 * lane - 128);
  f32x4 nc = {0.f, 0.f, 0.f, 0.f};
  float denc = 0.f;
  if (wave < nsplit) {
    nc = *reinterpret_cast<const f32x4*>(nump + ((size_t)wave * NN + i) * DQK + 4 * lane);
    if (lane == 0) denc = denp[wave * NN + i];
  }
  for (int p = wave; p < cnt; p += 4) {
    if (!keepf[p]) continue;
    float delta = ess[p] * expm1f(bs[p]);
    denc += delta;
    f32x4 v = *reinterpret_cast<const f32x4*>(vbase + (size_t)js[p] * DD);
    nc += delta * v;
  }
  ncl[wave][lane] = nc;
  if (lane == 0) dcl[wave] = denc;
  __syncthreads();
  if (wave == 0) {
    f32x4 nd = ncl[0][lane] + ncl[1][lane] + ncl[2][lane] + ncl[3][lane];
    float den = dcl[0] + dcl[1] + dcl[2] + dcl[3];
    f32x4 res = nd * (1.0f / den);
    if (lane < 32)
      *reinterpret_cast<f32x4*>(out + (size_t)i * DD + 4 * lane) = res;
    else
      *reinterpret_cast<f32x4*>(out + (size_t)NN * DD + (size_t)i * DD + 4 * lane - 128) = res;
  }
}

// ---------------- workspace layout -------------------------------------------
constexpr size_t OFF_QK = 0;                                  // 4 MiB bf16
constexpr size_t OFF_VT = (size_t)NN * DQK * 2;               // 4 MiB bf16
constexpr size_t OFF_BIAS = OFF_VT + (size_t)DQK * NN * 2;    // 1 MiB f32
constexpr size_t OFF_CNT = OFF_BIAS + (size_t)EE * 4;
constexpr size_t OFF_SLOT = OFF_CNT + (size_t)NN * 4;
constexpr size_t OFF_NUMP = (OFF_SLOT + (size_t)NN * CAP * 4 + 255) & ~(size_t)255;
constexpr size_t WS_NEED4 = OFF_NUMP + 4ull * NN * DQK * 4 + 4ull * NN * 4;
constexpr size_t WS_NEED2 = OFF_NUMP + 2ull * NN * DQK * 4 + 2ull * NN * 4;

extern "C" void kernel_launch(void* const* d_in, const int* in_sizes, int n_in,
                              void* d_out, int out_size, void* d_ws, size_t ws_size,
                              hipStream_t stream) {
  const float* mag = (const float*)d_in[0];
  const float* phase = (const float*)d_in[1];
  const int* eidx = (const int*)d_in[2];
  const float* rbf = (const float*)d_in[3];
  const float* W1 = (const float*)d_in[4];
  const float* b1 = (const float*)d_in[5];
  const float* W2 = (const float*)d_in[6];
  const float* b2 = (const float*)d_in[7];
  float* out = (float*)d_out;
  char* ws = (char*)d_ws;
  if (ws_size < WS_NEED2) return;
  int nsplit = (ws_size >= WS_NEED4) ? 4 : 2;

  short* qkb = (short*)(ws + OFF_QK);
  short* vtb = (short*)(ws + OFF_VT);
  float* bias = (float*)(ws + OFF_BIAS);
  int* cnt = (int*)(ws + OFF_CNT);
  int* slot = (int*)(ws + OFF_SLOT);
  float* nump = (float*)(ws + OFF_NUMP);
  float* denp = (float*)(ws + OFF_NUMP + (size_t)nsplit * NN * DQK * 4);

  hipMemsetAsync(cnt, 0, (size_t)NN * 4, stream);
  k1_mega<<<5632, 256, 0, stream>>>(mag, phase, qkb, vtb, rbf, W1, b1, W2, b2,
                                    eidx, bias, cnt, slot);
  if (nsplit == 4)
    k5_flash<4><<<(NN / TBM) * 4, 512, 0, stream>>>(qkb, vtb, nump, denp);
  else
    k5_flash<2><<<(NN / TBM) * 2, 512, 0, stream>>>(qkb, vtb, nump, denp);
  k6_combine<<<NN, 256, 0, stream>>>(eidx, bias, cnt, slot, qkb, mag, phase, nump,
                                     denp, out, nsplit);
}

// Round 8
// 292.764 us; speedup vs baseline: 1.9576x; 1.0411x over previous
//
#include <hip/hip_runtime.h>
#include <hip/hip_bf16.h>

#define NN 8192
#define DD 128
#define DQK 256
#define EE 262144
#define EDGE_DIM 50
#define HID 32
#define CAP 96                               // per-row edge cap (Poisson(32))
#define SCALE 0.08838834764831845f          // 1/sqrt(128)
#define SCALE_LOG2E 0.12752455522410585f    // SCALE * log2(e)

using f32x4 = __attribute__((ext_vector_type(4))) float;
using f32x2 = __attribute__((ext_vector_type(2))) float;
using bf16x8 = __attribute__((ext_vector_type(8))) short;  // 8 bf16 = 4 VGPRs
using s16x4 = __attribute__((ext_vector_type(4))) short;

static __device__ __forceinline__ short f2b(float f) {
  __hip_bfloat16 h = __float2bfloat16(f);
  return __builtin_bit_cast(short, h);
}
static __device__ __forceinline__ float b2f(short s) {
  unsigned u = ((unsigned)(unsigned short)s) << 16;
  return __builtin_bit_cast(float, u);
}
// async global->LDS, 16B per lane; lds dest = wave-uniform base + lane*16
static __device__ __forceinline__ void gll(const short* g, short* l) {
  __builtin_amdgcn_global_load_lds(
      (const __attribute__((address_space(1))) void*)g,
      (__attribute__((address_space(3))) void*)l, 16, 0, 0);
}

// ---------------- K1: heterogeneous prep + MLP, one dispatch -----------------
// blocks [0,4096):    qkb[n][0:128]=mag*cos, [128:256]=mag*sin (elementwise)
// blocks [4096,4608): vtb[f][n] transpose via 64x64 LDS tiles
// blocks [4608,5632): edge MLP bias + bucket scatter (cnt pre-zeroed by memset)
__global__ __launch_bounds__(256) void k1_mega(
    const float* __restrict__ mag, const float* __restrict__ phase,
    short* __restrict__ qkb, short* __restrict__ vtb,
    const float* __restrict__ rbf, const float* __restrict__ W1,
    const float* __restrict__ b1, const float* __restrict__ W2,
    const float* __restrict__ b2, const int* __restrict__ eidx,
    float* __restrict__ bias, int* __restrict__ cnt, int* __restrict__ slot) {
  __shared__ float tile[64][65];
  __shared__ alignas(16) float w1s[EDGE_DIM * HID];
  __shared__ alignas(16) float b1s[HID];
  __shared__ alignas(16) float w2s[HID];
  __shared__ float b2s;
  int b = blockIdx.x;
  int tid = threadIdx.x;
  if (b < 4096) {
    int t = b * 256 + tid;
    int n = t >> 7, d = t & 127;
    float m = mag[t], p = phase[t];
    float sn, cs;
    __sincosf(p, &sn, &cs);
    qkb[(size_t)n * DQK + d] = f2b(m * cs);
    qkb[(size_t)n * DQK + 128 + d] = f2b(m * sn);
    return;
  }
  if (b < 4608) {
    int r = b - 4096;
    int bn = r & 127, bd = (r >> 7) & 1, sel = r >> 8;
    const float* src = sel ? phase : mag;
#pragma unroll
    for (int rep = 0; rep < 16; ++rep) {
      int idx = rep * 256 + tid;
      int rr = idx >> 6, c = idx & 63;
      tile[rr][c] = src[(size_t)(bn * 64 + rr) * DD + bd * 64 + c];
    }
    __syncthreads();
#pragma unroll
    for (int rep = 0; rep < 16; ++rep) {
      int idx = rep * 256 + tid;
      int rr = idx >> 6, c = idx & 63;
      vtb[(size_t)(sel * 128 + bd * 64 + rr) * NN + bn * 64 + c] = f2b(tile[c][rr]);
    }
    return;
  }
  // ---- MLP branch ----
  for (int k = tid; k < EDGE_DIM * HID; k += 256) w1s[k] = W1[k];
  if (tid < HID) { b1s[tid] = b1[tid]; w2s[tid] = W2[tid]; }
  if (tid == 0) b2s = b2[0];
  __syncthreads();
  int e = (b - 4608) * 256 + tid;
  const float* rrow = rbf + (size_t)e * EDGE_DIM;
  f32x4 r4[12];
#pragma unroll
  for (int k = 0; k < 12; ++k) r4[k] = *reinterpret_cast<const f32x4*>(rrow + 4 * k);
  f32x2 rt2 = *reinterpret_cast<const f32x2*>(rrow + 48);
  f32x4 h[8];
#pragma unroll
  for (int jj = 0; jj < 8; ++jj) h[jj] = reinterpret_cast<const f32x4*>(b1s)[jj];
#pragma unroll
  for (int k = 0; k < 12; ++k) {
#pragma unroll
    for (int qq = 0; qq < 4; ++qq) {
      const f32x4* wrow = reinterpret_cast<const f32x4*>(w1s + (4 * k + qq) * HID);
#pragma unroll
      for (int jj = 0; jj < 8; ++jj) h[jj] += r4[k][qq] * wrow[jj];
    }
  }
  {
    const f32x4* w48 = reinterpret_cast<const f32x4*>(w1s + 48 * HID);
    const f32x4* w49 = reinterpret_cast<const f32x4*>(w1s + 49 * HID);
#pragma unroll
    for (int jj = 0; jj < 8; ++jj) h[jj] += rt2.x * w48[jj] + rt2.y * w49[jj];
  }
  float outv = b2s;
#pragma unroll
  for (int jj = 0; jj < 8; ++jj) {
    f32x4 x = h[jj];
    f32x4 sl;
#pragma unroll
    for (int q = 0; q < 4; ++q) sl[q] = x[q] / (1.0f + __expf(-x[q]));
    f32x4 pr = sl * reinterpret_cast<const f32x4*>(w2s)[jj];
    outv += pr.x + pr.y + pr.z + pr.w;
  }
  bias[e] = outv;
  int i = eidx[e];
  int p = atomicAdd(&cnt[i], 1);
  if (p < CAP) slot[i * CAP + p] = e;
}

// ---------------- K5: fused dense flash, 2 blocks/CU -------------------------
// TBM=64 rows/block, 512 threads = 8 waves (2 row x 4 col). LDS exactly 80 KiB
// (Qs 32K + KV 32K + Ps 16K, dl overlaid on KV) -> 2 blocks/CU so barrier
// drains of one block overlap compute of the other. All staging via
// global_load_lds (lane-linear dests) + XOR group swizzle on reads.
constexpr int TBM = 64;
constexpr int TBN = 128;

template <int NSPLIT>
__global__ __launch_bounds__(512, 4) void k5_flash(
    const short* __restrict__ qk,  // [N][256] bf16
    const short* __restrict__ vt,  // [256][N] bf16
    float* __restrict__ nump,      // [NSPLIT][N][256]
    float* __restrict__ denp) {    // [NSPLIT][N]
  constexpr int QCOLS = NN / NSPLIT;
  constexpr int NCHUNK = QCOLS / TBN;
  constexpr int GPQ = 8 / NSPLIT;
  __shared__ alignas(16) short Qs[TBM * 256];     // 32 KiB, swizzled
  __shared__ alignas(16) short KV[2 * TBN * 64];  // 32 KiB: K dbuf / V subtile
  __shared__ alignas(16) short Ps[TBM * 128];     // 16 KiB, swizzled
  int b = blockIdx.x;
  int q = (b & 7) / GPQ;
  int rb = (b >> 3) * GPQ + (b & (GPQ - 1));
  int tid = threadIdx.x;
  int w = tid >> 6, lane = tid & 63;
  int wr = w >> 2, wc = w & 3;
  int l15 = lane & 15, quad = lane >> 4;
  int rsw = l15 & 7;  // read-side swizzle key (row&7 == l15&7 for all frags)
  int wbase = w * 64; // lane-linear staging base per wave
  int r0 = rb * TBM;
  int cbase = q * QCOLS;

  // ---- stage Q tile once: 4 passes x 8KB, direct to LDS ----
#pragma unroll
  for (int p = 0; p < 4; ++p) {
    int idx = p * 512 + tid;
    int row = idx >> 5, gs = idx & 31;
    gll(qk + (size_t)(r0 + row) * DQK + ((gs ^ (row & 7)) * 8),
        &Qs[(p * 512 + wbase) * 8]);
  }

  f32x4 o[2][4] = {};
  float den[2][4] = {};
  __syncthreads();

  for (int ch = 0; ch < NCHUNK; ++ch) {
    int c0 = cbase + ch * TBN;
    // ---- stage K slice bk=0 into buf0 ----
#pragma unroll
    for (int p = 0; p < 2; ++p) {
      int idx = p * 512 + tid;
      int col = idx >> 3, gs = idx & 7;
      gll(qk + (size_t)(c0 + col) * DQK + ((gs ^ (col & 7)) * 8),
          &KV[(p * 512 + wbase) * 8]);
    }
    __syncthreads();
    f32x4 s[2][2] = {};
#pragma unroll
    for (int bk = 0; bk < 4; ++bk) {
      int buf = bk & 1;
      if (bk < 3) {
        int nb = buf ^ 1;
#pragma unroll
        for (int p = 0; p < 2; ++p) {
          int idx = p * 512 + tid;
          int col = idx >> 3, gs = idx & 7;
          gll(qk + (size_t)(c0 + col) * DQK + (bk + 1) * 64 + ((gs ^ (col & 7)) * 8),
              &KV[nb * 8192 + (p * 512 + wbase) * 8]);
        }
      }
#pragma unroll
      for (int ks = 0; ks < 2; ++ks) {
        int g = ks * 4 + quad;
        bf16x8 a[2], bb[2];
#pragma unroll
        for (int rt = 0; rt < 2; ++rt)
          a[rt] = *(const bf16x8*)&Qs[(wr * 32 + rt * 16 + l15) * 256 +
                                      ((bk * 8 + g) ^ rsw) * 8];
#pragma unroll
        for (int ct = 0; ct < 2; ++ct)
          bb[ct] = *(const bf16x8*)&KV[buf * 8192 + (wc * 32 + ct * 16 + l15) * 64 +
                                       (g ^ rsw) * 8];
#pragma unroll
        for (int rt = 0; rt < 2; ++rt)
#pragma unroll
          for (int ct = 0; ct < 2; ++ct)
            s[rt][ct] = __builtin_amdgcn_mfma_f32_16x16x32_bf16(a[rt], bb[ct],
                                                                s[rt][ct], 0, 0, 0);
      }
      __syncthreads();
    }
    // ---- exp + P->LDS (C layout, swizzled groups) + den ----
#pragma unroll
    for (int rt = 0; rt < 2; ++rt)
#pragma unroll
      for (int ct = 0; ct < 2; ++ct) {
        int col = wc * 32 + ct * 16 + l15;
        int cg = col >> 3, co = col & 7;
#pragma unroll
        for (int r = 0; r < 4; ++r) {
          float pv = exp2f(s[rt][ct][r] * SCALE_LOG2E);
          den[rt][r] += pv;
          int row = wr * 32 + rt * 16 + quad * 4 + r;
          Ps[row * 128 + ((cg ^ (row & 7)) * 8 + co)] = f2b(pv);
        }
      }
    __syncthreads();
    // ---- PV: V subtiles of 64 cols, staged direct to LDS ----
#pragma unroll
    for (int jb = 0; jb < 2; ++jb) {
#pragma unroll
      for (int p = 0; p < 4; ++p) {
        int idx = p * 512 + tid;
        int feat = idx >> 3, gs = idx & 7;
        gll(vt + (size_t)feat * NN + c0 + jb * 64 + ((gs ^ (feat & 7)) * 8),
            &KV[(p * 512 + wbase) * 8]);
      }
      __syncthreads();
#pragma unroll
      for (int ks = 0; ks < 2; ++ks) {
        int g = ks * 4 + quad;
        bf16x8 pa[2], vb[4];
#pragma unroll
        for (int rt = 0; rt < 2; ++rt) {
          int row = wr * 32 + rt * 16 + l15;
          pa[rt] = *(const bf16x8*)&Ps[row * 128 +
                                       (((jb * 8 + g) ^ (row & 7)) * 8)];
        }
#pragma unroll
        for (int ft = 0; ft < 4; ++ft)
          vb[ft] = *(const bf16x8*)&KV[(wc * 64 + ft * 16 + l15) * 64 + (g ^ rsw) * 8];
#pragma unroll
        for (int rt = 0; rt < 2; ++rt)
#pragma unroll
          for (int ft = 0; ft < 4; ++ft)
            o[rt][ft] = __builtin_amdgcn_mfma_f32_16x16x32_bf16(pa[rt], vb[ft],
                                                                o[rt][ft], 0, 0, 0);
      }
      __syncthreads();
    }
  }
  // ---- epilogue: write partial num ----
  float* npB = nump + (size_t)q * NN * DQK;
#pragma unroll
  for (int rt = 0; rt < 2; ++rt)
#pragma unroll
    for (int ft = 0; ft < 4; ++ft) {
      int row = r0 + wr * 32 + rt * 16 + quad * 4;
      int feat = wc * 64 + ft * 16 + l15;
#pragma unroll
      for (int r = 0; r < 4; ++r)
        npB[(size_t)(row + r) * DQK + feat] = o[rt][ft][r];
    }
  // ---- den: reduce l15 within quad, then across col-waves (dl overlays KV) --
  float* dl = reinterpret_cast<float*>(KV);  // [4][TBM], KV dead at epilogue
#pragma unroll
  for (int rt = 0; rt < 2; ++rt)
#pragma unroll
    for (int r = 0; r < 4; ++r) {
      float d = den[rt][r];
      d += __shfl_xor(d, 1);
      d += __shfl_xor(d, 2);
      d += __shfl_xor(d, 4);
      d += __shfl_xor(d, 8);
      if (l15 == 0) dl[wc * TBM + wr * 32 + rt * 16 + quad * 4 + r] = d;
    }
  __syncthreads();
  if (tid < TBM) {
    float d = dl[0 * TBM + tid] + dl[1 * TBM + tid] + dl[2 * TBM + tid] +
              dl[3 * TBM + tid];
    denp[q * NN + r0 + tid] = d;
  }
}

// ---------------- K6: per-row edge dot + merge + correction + combine --------
__global__ __launch_bounds__(256) void k6_combine(
    const int* __restrict__ eidx, const float* __restrict__ bias,
    const int* __restrict__ cntArr, const int* __restrict__ slot,
    const short* __restrict__ qk, const float* __restrict__ mag,
    const float* __restrict__ phase, const float* __restrict__ nump,
    const float* __restrict__ denp, float* __restrict__ out, int nsplit) {
  __shared__ short qs[DQK];
  __shared__ int js[CAP];
  __shared__ float bs[CAP];
  __shared__ float ess[CAP];
  __shared__ int keepf[CAP];
  __shared__ f32x4 ncl[4][64];
  __shared__ float dcl[4];
  int i = blockIdx.x;
  int tid = threadIdx.x;
  int wave = tid >> 6;
  int lane = tid & 63;
  int cnt = cntArr[i];
  if (cnt > CAP) cnt = CAP;
  if (tid < DQK) qs[tid] = qk[(size_t)i * DQK + tid];
  for (int p = tid; p < cnt; p += 256) {
    int e = slot[i * CAP + p];
    js[p] = eidx[EE + e];
    bs[p] = bias[e];
  }
  __syncthreads();
  int sub = lane & 7;
  for (int p = wave * 8 + (lane >> 3); p < cnt; p += 32) {
    int j = js[p];
    const bf16x8* kb = reinterpret_cast<const bf16x8*>(qk + (size_t)j * DQK + sub * 32);
    const bf16x8* qa = reinterpret_cast<const bf16x8*>(qs + sub * 32);
    float sp = 0.f;
#pragma unroll
    for (int t = 0; t < 4; ++t) {
      bf16x8 qv = qa[t];
      bf16x8 kv = kb[t];
#pragma unroll
      for (int u = 0; u < 8; ++u) sp += b2f(qv[u]) * b2f(kv[u]);
    }
    sp += __shfl_xor(sp, 1);
    sp += __shfl_xor(sp, 2);
    sp += __shfl_xor(sp, 4);
    if (sub == 0) ess[p] = __expf(sp * SCALE);
  }
  __syncthreads();
  {
    float bsum = 0.f;
    int keep = 0;
    if (tid < cnt) {
      int j = js[tid];
      bsum = bs[tid];
      keep = 1;
      for (int qq = 0; qq < cnt; ++qq) {
        if (qq == tid || js[qq] != j) continue;
        if (qq < tid) { keep = 0; break; }
        bsum += bs[qq];
      }
    }
    __syncthreads();
    if (tid < cnt) { bs[tid] = bsum; keepf[tid] = keep; }
    __syncthreads();
  }
  const float* vbase = (lane < 32) ? (mag + 4 * lane) : (phase + 4 * lane - 128);
  f32x4 nc = {0.f, 0.f, 0.f, 0.f};
  float denc = 0.f;
  if (wave < nsplit) {
    nc = *reinterpret_cast<const f32x4*>(nump + ((size_t)wave * NN + i) * DQK + 4 * lane);
    if (lane == 0) denc = denp[wave * NN + i];
  }
  for (int p = wave; p < cnt; p += 4) {
    if (!keepf[p]) continue;
    float delta = ess[p] * expm1f(bs[p]);
    denc += delta;
    f32x4 v = *reinterpret_cast<const f32x4*>(vbase + (size_t)js[p] * DD);
    nc += delta * v;
  }
  ncl[wave][lane] = nc;
  if (lane == 0) dcl[wave] = denc;
  __syncthreads();
  if (wave == 0) {
    f32x4 nd = ncl[0][lane] + ncl[1][lane] + ncl[2][lane] + ncl[3][lane];
    float den = dcl[0] + dcl[1] + dcl[2] + dcl[3];
    f32x4 res = nd * (1.0f / den);
    if (lane < 32)
      *reinterpret_cast<f32x4*>(out + (size_t)i * DD + 4 * lane) = res;
    else
      *reinterpret_cast<f32x4*>(out + (size_t)NN * DD + (size_t)i * DD + 4 * lane - 128) = res;
  }
}

// ---------------- workspace layout -------------------------------------------
constexpr size_t OFF_QK = 0;                                  // 4 MiB bf16
constexpr size_t OFF_VT = (size_t)NN * DQK * 2;               // 4 MiB bf16
constexpr size_t OFF_BIAS = OFF_VT + (size_t)DQK * NN * 2;    // 1 MiB f32
constexpr size_t OFF_CNT = OFF_BIAS + (size_t)EE * 4;
constexpr size_t OFF_SLOT = OFF_CNT + (size_t)NN * 4;
constexpr size_t OFF_NUMP = (OFF_SLOT + (size_t)NN * CAP * 4 + 255) & ~(size_t)255;
constexpr size_t WS_NEED4 = OFF_NUMP + 4ull * NN * DQK * 4 + 4ull * NN * 4;
constexpr size_t WS_NEED2 = OFF_NUMP + 2ull * NN * DQK * 4 + 2ull * NN * 4;

extern "C" void kernel_launch(void* const* d_in, const int* in_sizes, int n_in,
                              void* d_out, int out_size, void* d_ws, size_t ws_size,
                              hipStream_t stream) {
  const float* mag = (const float*)d_in[0];
  const float* phase = (const float*)d_in[1];
  const int* eidx = (const int*)d_in[2];
  const float* rbf = (const float*)d_in[3];
  const float* W1 = (const float*)d_in[4];
  const float* b1 = (const float*)d_in[5];
  const float* W2 = (const float*)d_in[6];
  const float* b2 = (const float*)d_in[7];
  float* out = (float*)d_out;
  char* ws = (char*)d_ws;
  if (ws_size < WS_NEED2) return;
  int nsplit = (ws_size >= WS_NEED4) ? 4 : 2;

  short* qkb = (short*)(ws + OFF_QK);
  short* vtb = (short*)(ws + OFF_VT);
  float* bias = (float*)(ws + OFF_BIAS);
  int* cnt = (int*)(ws + OFF_CNT);
  int* slot = (int*)(ws + OFF_SLOT);
  float* nump = (float*)(ws + OFF_NUMP);
  float* denp = (float*)(ws + OFF_NUMP + (size_t)nsplit * NN * DQK * 4);

  hipMemsetAsync(cnt, 0, (size_t)NN * 4, stream);
  k1_mega<<<5632, 256, 0, stream>>>(mag, phase, qkb, vtb, rbf, W1, b1, W2, b2,
                                    eidx, bias, cnt, slot);
  if (nsplit == 4)
    k5_flash<4><<<(NN / TBM) * 4, 512, 0, stream>>>(qkb, vtb, nump, denp);
  else
    k5_flash<2><<<(NN / TBM) * 2, 512, 0, stream>>>(qkb, vtb, nump, denp);
  k6_combine<<<NN, 256, 0, stream>>>(eidx, bias, cnt, slot, qkb, mag, phase, nump,
                                     denp, out, nsplit);
}